// Round 5
// baseline (725.187 us; speedup 1.0000x reference)
//
#include <hip/hip_runtime.h>

#define NN 4096
#define HH 256
#define EE 131072

__device__ __constant__ float LN_EPS = 1e-5f;
#define ATT_SCALE 0.08838834764831845f
#define ATT_SHIFT 30.0f

typedef __attribute__((ext_vector_type(8))) short bf16x8_t;
typedef __attribute__((ext_vector_type(4))) float f32x4_t;

__device__ inline ushort f2b(float f) {
  uint u = __float_as_uint(f);
  uint r = (u + 0x7FFF + ((u >> 16) & 1)) >> 16;
  return (ushort)r;
}
__device__ inline float b2f(ushort u) { return __uint_as_float((uint)u << 16); }

// ---------------- CSR build ----------------
__global__ void hist_kernel(const int* __restrict__ ei, int* __restrict__ cnt) {
  int e = blockIdx.x * blockDim.x + threadIdx.x;
  if (e < EE) atomicAdd(&cnt[ei[EE + e]], 1);
}

__global__ __launch_bounds__(1024) void scan_kernel(int* __restrict__ cnt_cursor,
                                                    int* __restrict__ rowptr,
                                                    float* __restrict__ invdeg) {
  __shared__ int part[1024];
  int t = threadIdx.x;
  int base = t * 4;
  int cs[4];
  int s = 0;
  for (int u = 0; u < 4; ++u) { cs[u] = cnt_cursor[base + u]; s += cs[u]; }
  part[t] = s;
  __syncthreads();
  for (int off = 1; off < 1024; off <<= 1) {
    int add = (t >= off) ? part[t - off] : 0;
    int v = part[t];
    __syncthreads();
    part[t] = v + add;
    __syncthreads();
  }
  int excl = (t > 0) ? part[t - 1] : 0;
  for (int u = 0; u < 4; ++u) {
    rowptr[base + u] = excl;
    cnt_cursor[base + u] = excl;
    invdeg[base + u] = 1.0f / (float)max(cs[u], 1);
    excl += cs[u];
  }
  if (t == 1023) rowptr[NN] = excl;
}

__global__ void fill_kernel(const int* __restrict__ ei, int* __restrict__ cursor,
                            int* __restrict__ col) {
  int e = blockIdx.x * blockDim.x + threadIdx.x;
  if (e < EE) {
    int d = ei[EE + e];
    int p = atomicAdd(&cursor[d], 1);
    col[p] = ei[e];
  }
}

// ---------------- casts ----------------
__global__ __launch_bounds__(256) void castw(const float* __restrict__ in,
                                             ushort* __restrict__ out) {
  int i4 = (blockIdx.x * 256 + threadIdx.x) * 4;
  float4 v = *(const float4*)(in + i4);
  ushort4 w;
  w.x = f2b(v.x); w.y = f2b(v.y); w.z = f2b(v.z); w.w = f2b(v.w);
  *(ushort4*)(out + i4) = w;
}

// conv weight repack: out[j][o][ks*256+ii] = w[j][o][ii][ks]
__global__ __launch_bounds__(256) void castconv(const float* __restrict__ w,
                                                ushort* __restrict__ o) {
  int idx = blockIdx.x * 256 + threadIdx.x;  // 3*256*768
  int j = idx / 196608;
  int rem = idx - j * 196608;
  int oc = rem / 768;
  int kk = rem - oc * 768;
  int ks = kk >> 8, ii = kk & 255;
  o[idx] = f2b(w[j * 196608 + oc * 768 + ii * 3 + ks]);
}

// ---------------- neighbor mean aggregation (bf16 in, fp32 acc, bf16 out) ----------------
__global__ __launch_bounds__(64) void agg_kernel(const ushort* __restrict__ hb,
                                                 const int* __restrict__ rowptr,
                                                 const int* __restrict__ col,
                                                 const float* __restrict__ invdeg,
                                                 ushort* __restrict__ aggb) {
  int n = blockIdx.x;
  int t = threadIdx.x;
  int s = rowptr[n], e = rowptr[n + 1];
  float4 acc = make_float4(0.f, 0.f, 0.f, 0.f);
  for (int j = s; j < e; ++j) {
    int c = col[j];
    ushort4 v = *(const ushort4*)(hb + (size_t)c * HH + t * 4);
    acc.x += b2f(v.x); acc.y += b2f(v.y); acc.z += b2f(v.z); acc.w += b2f(v.w);
  }
  float id = invdeg[n];
  ushort4 w;
  w.x = f2b(acc.x * id); w.y = f2b(acc.y * id);
  w.z = f2b(acc.z * id); w.w = f2b(acc.w * id);
  *(ushort4*)(aggb + (size_t)n * HH + t * 4) = w;
}

// ---------------- bf16 MFMA GEMM: C[M,Nn] = A[M,K] B[Nn,K]^T + bias ----------------
__global__ __launch_bounds__(256) void gemm_mfma(
    const ushort* __restrict__ A0, const ushort* __restrict__ A1,
    const ushort* __restrict__ B0, const ushort* __restrict__ B1,
    const float* __restrict__ bias, float* __restrict__ Cf, ushort* __restrict__ Cb,
    int M, int Nn, int K, int KHA, int KHB, int relu) {
  __shared__ ushort Alds[64][40];
  __shared__ ushort Blds[128][40];
  int t = threadIdx.x;
  int w = t >> 6, l = t & 63, quad = l >> 4, lr = l & 15;
  int wm = w & 1, wn = w >> 1;
  int m0 = blockIdx.x * 64, n0 = blockIdx.y * 128;
  int sr = t >> 2, sc8 = (t & 3) * 8;
  f32x4_t acc[2][4];
#pragma unroll
  for (int s = 0; s < 2; ++s)
#pragma unroll
    for (int q = 0; q < 4; ++q) acc[s][q] = (f32x4_t){0.f, 0.f, 0.f, 0.f};

  for (int k0 = 0; k0 < K; k0 += 32) {
    int kk = k0 + sc8;
    const ushort* ap = (kk < KHA) ? (A0 + (size_t)(m0 + sr) * KHA + kk)
                                  : (A1 + (size_t)(m0 + sr) * (K - KHA) + (kk - KHA));
    uint4 av = *(const uint4*)ap;
    const ushort* bp0 = (kk < KHB) ? (B0 + (size_t)(n0 + sr) * KHB + kk)
                                   : (B1 + (size_t)(n0 + sr) * (K - KHB) + (kk - KHB));
    uint4 bv0 = *(const uint4*)bp0;
    const ushort* bp1 = (kk < KHB) ? (B0 + (size_t)(n0 + 64 + sr) * KHB + kk)
                                   : (B1 + (size_t)(n0 + 64 + sr) * (K - KHB) + (kk - KHB));
    uint4 bv1 = *(const uint4*)bp1;
    __syncthreads();
    *(uint4*)&Alds[sr][sc8] = av;
    *(uint4*)&Blds[sr][sc8] = bv0;
    *(uint4*)&Blds[64 + sr][sc8] = bv1;
    __syncthreads();
    bf16x8_t af[2], bf[4];
#pragma unroll
    for (int s = 0; s < 2; ++s)
      af[s] = *(const bf16x8_t*)&Alds[wm * 32 + s * 16 + lr][quad * 8];
#pragma unroll
    for (int q = 0; q < 4; ++q)
      bf[q] = *(const bf16x8_t*)&Blds[wn * 64 + q * 16 + lr][quad * 8];
#pragma unroll
    for (int s = 0; s < 2; ++s)
#pragma unroll
      for (int q = 0; q < 4; ++q)
        acc[s][q] = __builtin_amdgcn_mfma_f32_16x16x32_bf16(af[s], bf[q], acc[s][q], 0, 0, 0);
  }
#pragma unroll
  for (int s = 0; s < 2; ++s) {
#pragma unroll
    for (int q = 0; q < 4; ++q) {
      int n = n0 + wn * 64 + q * 16 + lr;
      float bb = bias[n];
#pragma unroll
      for (int r = 0; r < 4; ++r) {
        int m = m0 + wm * 32 + s * 16 + quad * 4 + r;
        float v = acc[s][q][r] + bb;
        if (relu) v = fmaxf(v, 0.f);
        if (Cf) Cf[(size_t)m * Nn + n] = v;
        if (Cb) Cb[(size_t)m * Nn + n] = f2b(v);
      }
    }
  }
}

// ---------------- dual independent 256x256 GEMMs (SAGE layer), z picks operand set ----------------
__global__ __launch_bounds__(256) void gemm_dual(
    const ushort* __restrict__ A0, const ushort* __restrict__ B0,
    const float* __restrict__ bias0, float* __restrict__ C0,
    const ushort* __restrict__ A1, const ushort* __restrict__ B1,
    float* __restrict__ C1) {
  __shared__ ushort Alds[64][40];
  __shared__ ushort Blds[128][40];
  int t = threadIdx.x;
  int w = t >> 6, l = t & 63, quad = l >> 4, lr = l & 15;
  int wm = w & 1, wn = w >> 1;
  int m0 = blockIdx.x * 64, n0 = blockIdx.y * 128;
  int z = blockIdx.z;
  const ushort* A = z ? A1 : A0;
  const ushort* B = z ? B1 : B0;
  float* C = z ? C1 : C0;
  int sr = t >> 2, sc8 = (t & 3) * 8;
  f32x4_t acc[2][4];
#pragma unroll
  for (int s = 0; s < 2; ++s)
#pragma unroll
    for (int q = 0; q < 4; ++q) acc[s][q] = (f32x4_t){0.f, 0.f, 0.f, 0.f};

  for (int k0 = 0; k0 < 256; k0 += 32) {
    int kk = k0 + sc8;
    uint4 av = *(const uint4*)(A + (size_t)(m0 + sr) * 256 + kk);
    uint4 bv0 = *(const uint4*)(B + (size_t)(n0 + sr) * 256 + kk);
    uint4 bv1 = *(const uint4*)(B + (size_t)(n0 + 64 + sr) * 256 + kk);
    __syncthreads();
    *(uint4*)&Alds[sr][sc8] = av;
    *(uint4*)&Blds[sr][sc8] = bv0;
    *(uint4*)&Blds[64 + sr][sc8] = bv1;
    __syncthreads();
    bf16x8_t af[2], bf[4];
#pragma unroll
    for (int s = 0; s < 2; ++s)
      af[s] = *(const bf16x8_t*)&Alds[wm * 32 + s * 16 + lr][quad * 8];
#pragma unroll
    for (int q = 0; q < 4; ++q)
      bf[q] = *(const bf16x8_t*)&Blds[wn * 64 + q * 16 + lr][quad * 8];
#pragma unroll
    for (int s = 0; s < 2; ++s)
#pragma unroll
      for (int q = 0; q < 4; ++q)
        acc[s][q] = __builtin_amdgcn_mfma_f32_16x16x32_bf16(af[s], bf[q], acc[s][q], 0, 0, 0);
  }
#pragma unroll
  for (int s = 0; s < 2; ++s) {
#pragma unroll
    for (int q = 0; q < 4; ++q) {
      int n = n0 + wn * 64 + q * 16 + lr;
      float bb = z ? 0.f : bias0[n];
#pragma unroll
      for (int r = 0; r < 4; ++r) {
        int m = m0 + wm * 32 + s * 16 + quad * 4 + r;
        C[(size_t)m * 256 + n] = acc[s][q][r] + bb;
      }
    }
  }
}

// ---------------- conv1d(k=3,pad=1) as MFMA GEMM, z-split K (2x384), raw fp32 out ----------------
__global__ __launch_bounds__(256) void gemm_conv_mfma(
    const ushort* __restrict__ Ab, const ushort* __restrict__ B,
    const float* __restrict__ bias, float* __restrict__ C0, float* __restrict__ C1) {
  __shared__ ushort Alds[64][40];
  __shared__ ushort Blds[128][40];
  int t = threadIdx.x;
  int w = t >> 6, l = t & 63, quad = l >> 4, lr = l & 15;
  int wm = w & 1, wn = w >> 1;
  int m0 = blockIdx.x * 64, n0 = blockIdx.y * 128;
  int z = blockIdx.z;
  float* C = z ? C1 : C0;
  int sr = t >> 2, sc8 = (t & 3) * 8;
  f32x4_t acc[2][4];
#pragma unroll
  for (int s = 0; s < 2; ++s)
#pragma unroll
    for (int q = 0; q < 4; ++q) acc[s][q] = (f32x4_t){0.f, 0.f, 0.f, 0.f};

  for (int k0 = 0; k0 < 384; k0 += 32) {
    int kk = z * 384 + k0 + sc8;
    int ks = kk >> 8, ii = kk & 255;
    int nr = m0 + sr + ks - 1;
    uint4 av = make_uint4(0u, 0u, 0u, 0u);
    if (nr >= 0 && nr < NN) av = *(const uint4*)(Ab + (size_t)nr * HH + ii);
    uint4 bv0 = *(const uint4*)(B + (size_t)(n0 + sr) * 768 + kk);
    uint4 bv1 = *(const uint4*)(B + (size_t)(n0 + 64 + sr) * 768 + kk);
    __syncthreads();
    *(uint4*)&Alds[sr][sc8] = av;
    *(uint4*)&Blds[sr][sc8] = bv0;
    *(uint4*)&Blds[64 + sr][sc8] = bv1;
    __syncthreads();
    bf16x8_t af[2], bf[4];
#pragma unroll
    for (int s = 0; s < 2; ++s)
      af[s] = *(const bf16x8_t*)&Alds[wm * 32 + s * 16 + lr][quad * 8];
#pragma unroll
    for (int q = 0; q < 4; ++q)
      bf[q] = *(const bf16x8_t*)&Blds[wn * 64 + q * 16 + lr][quad * 8];
#pragma unroll
    for (int s = 0; s < 2; ++s)
#pragma unroll
      for (int q = 0; q < 4; ++q)
        acc[s][q] = __builtin_amdgcn_mfma_f32_16x16x32_bf16(af[s], bf[q], acc[s][q], 0, 0, 0);
  }
#pragma unroll
  for (int s = 0; s < 2; ++s) {
#pragma unroll
    for (int q = 0; q < 4; ++q) {
      int n = n0 + wn * 64 + q * 16 + lr;
      float bb = z ? 0.f : bias[n];
#pragma unroll
      for (int r = 0; r < 4; ++r) {
        int m = m0 + wm * 32 + s * 16 + quad * 4 + r;
        C[(size_t)m * HH + n] = acc[s][q][r] + bb;
      }
    }
  }
}

// ---------------- fp32 tiled GEMM (fuse head only) ----------------
__global__ __launch_bounds__(256) void gemm_std(
    const float* __restrict__ A0, const float* __restrict__ B0,
    const float* __restrict__ bias, float* __restrict__ C,
    int M, int Nn, int K) {
  __shared__ float As[16][68];
  __shared__ float Bs[16][68];
  int t = threadIdx.x;
  int m0 = blockIdx.x * 64, n0 = blockIdx.y * 64;
  int ty = t >> 4, tx = t & 15;
  int lr = t >> 2, lc4 = (t & 3) * 4;
  float acc[4][4] = {};
  for (int k0 = 0; k0 < K; k0 += 16) {
    int kk = k0 + lc4;
    float4 va = *(const float4*)(A0 + (size_t)(m0 + lr) * K + kk);
    As[lc4 + 0][lr] = va.x; As[lc4 + 1][lr] = va.y;
    As[lc4 + 2][lr] = va.z; As[lc4 + 3][lr] = va.w;
    float4 vb = *(const float4*)(B0 + (size_t)(n0 + lr) * K + kk);
    Bs[lc4 + 0][lr] = vb.x; Bs[lc4 + 1][lr] = vb.y;
    Bs[lc4 + 2][lr] = vb.z; Bs[lc4 + 3][lr] = vb.w;
    __syncthreads();
#pragma unroll
    for (int k = 0; k < 16; ++k) {
      float4 a4 = *(const float4*)&As[k][4 * ty];
      float4 b4 = *(const float4*)&Bs[k][4 * tx];
      float av[4] = {a4.x, a4.y, a4.z, a4.w};
      float bv[4] = {b4.x, b4.y, b4.z, b4.w};
#pragma unroll
      for (int i = 0; i < 4; ++i)
#pragma unroll
        for (int j = 0; j < 4; ++j) acc[i][j] += av[i] * bv[j];
    }
    __syncthreads();
  }
#pragma unroll
  for (int i = 0; i < 4; ++i) {
    int m = m0 + 4 * ty + i;
    float o[4];
#pragma unroll
    for (int j = 0; j < 4; ++j) o[j] = acc[i][j] + bias[n0 + 4 * tx + j];
    float4 o4 = make_float4(o[0], o[1], o[2], o[3]);
    *(float4*)(C + (size_t)m * Nn + n0 + 4 * tx) = o4;
  }
}

// ---------------- fused LayerNorm (+ x2 sum + pre-relu + optional relu+residual) ----------------
__global__ __launch_bounds__(256) void ln_fuse(
    const float* __restrict__ x, const float* __restrict__ x2,
    const float* __restrict__ g, const float* __restrict__ b,
    const float* __restrict__ res, float* __restrict__ outf, ushort* __restrict__ outb,
    int D, int do_ln, int relu_res, int prerelu) {
  int row = blockIdx.x, t = threadIdx.x;
  int nv = D >> 8;
  float vals[2];
  float s = 0.f, sq = 0.f;
  for (int u = 0; u < nv; ++u) {
    int c = t + (u << 8);
    float v = x[(size_t)row * D + c];
    if (x2) v += x2[(size_t)row * D + c];
    if (prerelu) v = fmaxf(v, 0.f);
    vals[u] = v; s += v; sq += v * v;
  }
  __shared__ float red[8];
  float m = 0.f, inv = 1.f;
  if (do_ln) {
    for (int off = 32; off >= 1; off >>= 1) {
      s += __shfl_xor(s, off);
      sq += __shfl_xor(sq, off);
    }
    int wid = t >> 6;
    if ((t & 63) == 0) { red[wid] = s; red[4 + wid] = sq; }
    __syncthreads();
    if (t == 0) {
      float S = red[0] + red[1] + red[2] + red[3];
      float Q = red[4] + red[5] + red[6] + red[7];
      float mm = S / D;
      float vv = Q / D - mm * mm;
      red[0] = mm;
      red[1] = rsqrtf(vv + LN_EPS);
    }
    __syncthreads();
    m = red[0]; inv = red[1];
  }
  for (int u = 0; u < nv; ++u) {
    int c = t + (u << 8);
    float y = vals[u];
    if (do_ln) y = (y - m) * inv * g[c] + b[c];
    if (relu_res) y = fmaxf(y, 0.f) + res[(size_t)row * D + c];
    if (outf) outf[(size_t)row * D + c] = y;
    if (outb) outb[(size_t)row * D + c] = f2b(y);
  }
}

// ---------------- K/V repack for fragment-direct attention ----------------
// Kt[head][kt][ks][key32][elem32]: fragment (ks,ct) for tile kt = 1KB contiguous.
// VtT[head][kt][d128][key32]: fragment (dt) for tile kt = 1KB contiguous.
__global__ __launch_bounds__(256) void kvpack(const ushort* __restrict__ qkvb,
                                              ushort* __restrict__ Kt,
                                              ushort* __restrict__ VtT) {
  int t = threadIdx.x;
  int n0 = blockIdx.x * 32;  // 32 global keys
  int by = blockIdx.y;       // 0..15
  int kt = n0 >> 5;
  // K repack: cols 512 + by*32 .. +31  (head = by>>2, ks = by&3)
  {
    int head = by >> 2, ks = by & 3;
    int key = t >> 3, e4 = (t & 7) * 4;
    uint2 v = *(const uint2*)(qkvb + (size_t)(n0 + key) * 1536 + 512 + head * 128 + ks * 32 + e4);
    *(uint2*)(Kt + ((((size_t)head * 128 + kt) * 4 + ks) * 32 + key) * 32 + e4) = v;
  }
  // V transpose: cols 1024 + by*32 .. +31
  __shared__ ushort tile[32][34];
  int d0 = by * 32;
  int tx = t & 31, ty = t >> 5;
#pragma unroll
  for (int u = 0; u < 4; ++u) {
    int r = ty + 8 * u;
    tile[r][tx] = qkvb[(size_t)(n0 + r) * 1536 + 1024 + d0 + tx];
  }
  __syncthreads();
#pragma unroll
  for (int u = 0; u < 4; ++u) {
    int dg = d0 + ty + 8 * u;
    int head = dg >> 7, dl = dg & 127;
    VtT[((((size_t)head * 128 + kt) * 128 + dl) << 5) + tx] = tile[tx][ty + 8 * u];
  }
}

// ---------------- bf16 MFMA flash attention (4 heads, hd=128), bf16 out ----------------
// v5: fragment-direct, 1024-thread blocks. 16 waves = 2 q-halves x 8 k-eighths;
// block covers 64 q-rows (halves L2 K/V traffic vs 32) and grid (64,4) = 256 blocks
// = 1 block/CU = 16 waves/CU = 4 waves/SIMD (2x latency hiding vs v4).
// Barrier-free main loop; fixed-shift softmax => 8 k-partials per q-half merge by
// addition in a chunked LDS reduction at the end.
__global__ __launch_bounds__(1024, 4) void attn_mfma(const ushort* __restrict__ qkvb,
                                                     const ushort* __restrict__ Kt,
                                                     const ushort* __restrict__ VtT,
                                                     ushort* __restrict__ Ob) {
  // loop phase: P[16][32][40] ushort (40.0 KB, wave-private slices, overlays OS)
  // merge phase: OS[16][32][34] f32 (69632 B) + Dsum[16][32] (2 KB) + invd[64] (256 B)
  __shared__ __align__(16) char smem[71936];
  int t = threadIdx.x;
  int w = t >> 6, l = t & 63;
  int quad = l >> 4, lr = l & 15;
  int qh = w >> 3, ke = w & 7;
  int head = blockIdx.y;
  int q0 = blockIdx.x * 64 + qh * 32;

  ushort* Pl = (ushort*)smem + w * 1280;  // [32][40] wave-private

  bf16x8_t qf[2][4];
#pragma unroll
  for (int s = 0; s < 2; ++s)
#pragma unroll
    for (int ks = 0; ks < 4; ++ks)
      qf[s][ks] = *(const bf16x8_t*)(qkvb + (size_t)(q0 + s * 16 + lr) * 1536 +
                                     head * 128 + ks * 32 + quad * 8);

  f32x4_t of[2][8];
#pragma unroll
  for (int s = 0; s < 2; ++s)
#pragma unroll
    for (int dt = 0; dt < 8; ++dt) of[s][dt] = (f32x4_t){0.f, 0.f, 0.f, 0.f};
  float den[2][4] = {{0.f, 0.f, 0.f, 0.f}, {0.f, 0.f, 0.f, 0.f}};

  const int lnoff = lr * 32 + quad * 8;  // lane offset within a 1KB fragment
  const int tile0 = ke * 16;             // this wave's k-eighth (16 tiles of 32 keys)

  for (int tt = 0; tt < 16; ++tt) {
    int kt = tile0 + tt;
    const ushort* kbase = Kt + (((size_t)head * 128 + kt) << 12);
    const ushort* vbase = VtT + (((size_t)head * 128 + kt) << 12);

    // K fragments
    bf16x8_t kf[4][2];
#pragma unroll
    for (int ks = 0; ks < 4; ++ks)
#pragma unroll
      for (int ct = 0; ct < 2; ++ct)
        kf[ks][ct] = *(const bf16x8_t*)(kbase + ks * 1024 + ct * 512 + lnoff);
    // V fragments issued early (consumed after QK+exp: latency hides under them)
    bf16x8_t vf[8];
#pragma unroll
    for (int dt = 0; dt < 8; ++dt)
      vf[dt] = *(const bf16x8_t*)(vbase + dt * 512 + lnoff);

    // QK^T: S[32 q-rows][32 keys]
    f32x4_t sf[2][2];
#pragma unroll
    for (int s = 0; s < 2; ++s)
#pragma unroll
      for (int ct = 0; ct < 2; ++ct) sf[s][ct] = (f32x4_t){0.f, 0.f, 0.f, 0.f};
    __builtin_amdgcn_s_setprio(1);
#pragma unroll
    for (int ks = 0; ks < 4; ++ks)
#pragma unroll
      for (int ct = 0; ct < 2; ++ct)
#pragma unroll
        for (int s = 0; s < 2; ++s)
          sf[s][ct] = __builtin_amdgcn_mfma_f32_16x16x32_bf16(qf[s][ks], kf[ks][ct], sf[s][ct], 0, 0, 0);
    __builtin_amdgcn_s_setprio(0);

    // softmax exp (fixed shift), P -> wave-private LDS, per-lane den partials
#pragma unroll
    for (int s = 0; s < 2; ++s)
#pragma unroll
      for (int ct = 0; ct < 2; ++ct)
#pragma unroll
        for (int r = 0; r < 4; ++r) {
          float e = __expf(sf[s][ct][r] * ATT_SCALE - ATT_SHIFT);
          Pl[(s * 16 + quad * 4 + r) * 40 + ct * 16 + lr] = f2b(e);
          den[s][r] += e;
        }

    // PV: O[32 rows][128 d] += P[32][32] * V[32][128]
    __builtin_amdgcn_s_setprio(1);
#pragma unroll
    for (int s = 0; s < 2; ++s) {
      bf16x8_t pf = *(const bf16x8_t*)&Pl[(s * 16 + lr) * 40 + quad * 8];
#pragma unroll
      for (int dt = 0; dt < 8; ++dt)
        of[s][dt] = __builtin_amdgcn_mfma_f32_16x16x32_bf16(pf, vf[dt], of[s][dt], 0, 0, 0);
    }
    __builtin_amdgcn_s_setprio(0);
  }

  // finish den: reduce over the 16 lr lanes (per row s*16+quad*4+r)
#pragma unroll
  for (int mask = 1; mask < 16; mask <<= 1)
#pragma unroll
    for (int s = 0; s < 2; ++s)
#pragma unroll
      for (int r = 0; r < 4; ++r) den[s][r] += __shfl_xor(den[s][r], mask);

  // ---- merge the 8 k-partials per q-half (pure addition: fixed-shift softmax) ----
  __syncthreads();  // all waves' loops done; P region dead; safe to overlay OS
  float* OS   = (float*)smem;             // [16][32][34]
  float* Dsum = (float*)(smem + 69632);   // [16][32]
  float* invd = (float*)(smem + 71680);   // [64]
  if (lr == 0) {
#pragma unroll
    for (int s = 0; s < 2; ++s)
#pragma unroll
      for (int r = 0; r < 4; ++r) Dsum[w * 32 + s * 16 + quad * 4 + r] = den[s][r];
  }
  __syncthreads();
  if (t < 64) {
    int oh = t >> 5, row = t & 31;
    float sden = 0.f;
#pragma unroll
    for (int j = 0; j < 8; ++j) sden += Dsum[(oh * 8 + j) * 32 + row];
    invd[t] = 1.0f / sden;
  }
  // O merge in 4 chunks of 32 columns (2 dt each); OS reused per chunk
  for (int dc = 0; dc < 4; ++dc) {
#pragma unroll
    for (int s = 0; s < 2; ++s)
#pragma unroll
      for (int u = 0; u < 2; ++u) {
        int dt = dc * 2 + u;
#pragma unroll
        for (int r = 0; r < 4; ++r)
          OS[w * 1088 + (s * 16 + quad * 4 + r) * 34 + u * 16 + lr] = of[s][dt][r];
      }
    __syncthreads();  // (also publishes invd on first iteration)
#pragma unroll
    for (int it = 0; it < 2; ++it) {
      int idx = t + it * 1024;
      int orow = idx >> 5, c2 = idx & 31;
      int oh = orow >> 5, row = orow & 31;
      float sum = 0.f;
#pragma unroll
      for (int j = 0; j < 8; ++j) sum += OS[(oh * 8 + j) * 1088 + row * 34 + c2];
      Ob[(size_t)(blockIdx.x * 64 + orow) * 512 + head * 128 + dc * 32 + c2] =
          f2b(sum * invd[orow]);
    }
    __syncthreads();
  }
}

// ---------------- launch ----------------
extern "C" void kernel_launch(void* const* d_in, const int* in_sizes, int n_in,
                              void* d_out, int out_size, void* d_ws, size_t ws_size,
                              hipStream_t stream) {
  const float* x          = (const float*)d_in[0];
  const int*   ei         = (const int*)d_in[1];
  const float* sage_wl    = (const float*)d_in[2];
  const float* sage_wr    = (const float*)d_in[3];
  const float* sage_bl    = (const float*)d_in[4];
  const float* ln_g       = (const float*)d_in[5];
  const float* ln_b       = (const float*)d_in[6];
  const float* conv_w     = (const float*)d_in[7];
  const float* conv_b     = (const float*)d_in[8];
  const float* cnorm_g    = (const float*)d_in[9];
  const float* cnorm_b    = (const float*)d_in[10];
  const float* in_proj_w  = (const float*)d_in[11];
  const float* in_proj_b  = (const float*)d_in[12];
  const float* out_proj_w = (const float*)d_in[13];
  const float* out_proj_b = (const float*)d_in[14];
  const float* anorm_g    = (const float*)d_in[15];
  const float* anorm_b    = (const float*)d_in[16];
  const float* fuse_w     = (const float*)d_in[17];
  const float* fuse_b     = (const float*)d_in[18];
  float* out = (float*)d_out;

  char* ws = (char*)d_ws;
  const size_t MB = 1 << 20;
  int*    rowptr = (int*)(ws + 0);
  int*    cnt    = (int*)(ws + 65536);
  int*    col    = (int*)(ws + 131072);
  float*  invdeg = (float*)(ws + 786432);
  float*  h    = (float*)(ws + 1 * MB);
  ushort* hb   = (ushort*)(ws + 5 * MB);
  ushort* aggb = (ushort*)(ws + 7 * MB);
  float*  tmp  = (float*)(ws + 9 * MB);
  ushort* c0b  = (ushort*)(ws + 13 * MB);
  ushort* c1b  = (ushort*)(ws + 15 * MB);
  ushort* qkvb = (ushort*)(ws + 17 * MB);
  float*  op   = (float*)(ws + 17 * MB);    // reuses qkvb after attention
  float*  tmp2 = (float*)(ws + 25 * MB);    // split-K partial (qkvb tail, dead pre-in_proj)
  ushort* Kt   = (ushort*)(ws + 1 * MB);    // reuses h (dead after GNN): 4MB
  ushort* Vt   = (ushort*)(ws + 29 * MB);   // VtT tile-major V (4MB)
  ushort* aob  = (ushort*)(ws + 33 * MB);
  ushort* wlb  = (ushort*)(ws + 37 * MB);            // 6*256*256 = 786KB
  ushort* wrb  = (ushort*)(ws + 37 * MB + 786432);   // 786KB
  ushort* cvb  = (ushort*)(ws + 37 * MB + 1572864);  // 3*256*768 = 1.125MB
  ushort* ipb  = (ushort*)(ws + 37 * MB + 2752512);  // 1536*512 = 1.5MB
  ushort* opb  = (ushort*)(ws + 37 * MB + 4325376);  // 512*512 = 0.5MB

  // weight casts
  castw<<<(6 * 256 * 256) / 1024, 256, 0, stream>>>(sage_wl, wlb);
  castw<<<(6 * 256 * 256) / 1024, 256, 0, stream>>>(sage_wr, wrb);
  castconv<<<(3 * 256 * 768) / 256, 256, 0, stream>>>(conv_w, cvb);
  castw<<<(1536 * 512) / 1024, 256, 0, stream>>>(in_proj_w, ipb);
  castw<<<(512 * 512) / 1024, 256, 0, stream>>>(out_proj_w, opb);

  // CSR
  hipMemsetAsync(cnt, 0, NN * sizeof(int), stream);
  hist_kernel<<<EE / 256, 256, 0, stream>>>(ei, cnt);
  scan_kernel<<<1, 1024, 0, stream>>>(cnt, rowptr, invdeg);
  fill_kernel<<<EE / 256, 256, 0, stream>>>(ei, cnt, col);
  hipMemcpyAsync(h, x, (size_t)NN * HH * sizeof(float), hipMemcpyDeviceToDevice, stream);
  castw<<<(NN * HH) / 1024, 256, 0, stream>>>(x, hb);

  // GNN: 6 SAGE layers (z-split: z=0 agg@wl^T+bias -> tmp, z=1 h@wr^T -> tmp2)
  for (int i = 0; i < 6; ++i) {
    agg_kernel<<<NN, 64, 0, stream>>>(hb, rowptr, col, invdeg, aggb);
    gemm_dual<<<dim3(64, 2, 2), 256, 0, stream>>>(
        aggb, wlb + (size_t)i * HH * HH, sage_bl + i * HH, tmp,
        hb, wrb + (size_t)i * HH * HH, tmp2);
    int do_ln = (i < 5) ? 1 : 0;
    const float* gp = do_ln ? (ln_g + i * HH) : ln_g;
    const float* bp = do_ln ? (ln_b + i * HH) : ln_b;
    ln_fuse<<<NN, 256, 0, stream>>>(tmp, tmp2, gp, bp, h, h, hb, HH, do_ln, 1, 0);
  }

  // CNN: 3 conv layers (z-split K: 2x384; combiner does relu(sum+bias) then LN)
  const ushort* cin = hb;
  ushort* couts[3] = {c0b, c1b, c0b};
  for (int j = 0; j < 3; ++j) {
    gemm_conv_mfma<<<dim3(64, 2, 2), 256, 0, stream>>>(
        cin, cvb + (size_t)j * HH * 768, conv_b + j * HH, tmp, tmp2);
    ln_fuse<<<NN, 256, 0, stream>>>(tmp, tmp2, cnorm_g + j * HH, cnorm_b + j * HH,
                                    nullptr, nullptr, couts[j], HH, 1, 0, 1);
    cin = couts[j];
  }

  // attention
  gemm_mfma<<<dim3(64, 12), 256, 0, stream>>>(
      hb, c0b, ipb, nullptr, in_proj_b, nullptr, qkvb, NN, 1536, 512, 256, 1536 * 0 + 512, 0);
  kvpack<<<dim3(NN / 32, 16), 256, 0, stream>>>(qkvb, Kt, Vt);
  attn_mfma<<<dim3(64, 4), 1024, 0, stream>>>(qkvb, Kt, Vt, aob);

  gemm_mfma<<<dim3(64, 4), 256, 0, stream>>>(
      aob, nullptr, opb, nullptr, out_proj_b, op, nullptr, NN, 512, 512, 512, 512, 0);
  ln_fuse<<<NN, 256, 0, stream>>>(op, nullptr, anorm_g, anorm_b, nullptr, op, nullptr, 512, 1, 0, 0);
  gemm_std<<<dim3(64, 1), 256, 0, stream>>>(op, fuse_w, fuse_b, out, NN, 64, 512);
}

// Round 6
// 721.976 us; speedup vs baseline: 1.0044x; 1.0044x over previous
//
#include <hip/hip_runtime.h>

#define NN 4096
#define HH 256
#define EE 131072

__device__ __constant__ float LN_EPS = 1e-5f;
#define ATT_SCALE 0.08838834764831845f
#define ATT_SHIFT 30.0f

typedef __attribute__((ext_vector_type(8))) short bf16x8_t;
typedef __attribute__((ext_vector_type(4))) float f32x4_t;

__device__ inline ushort f2b(float f) {
  uint u = __float_as_uint(f);
  uint r = (u + 0x7FFF + ((u >> 16) & 1)) >> 16;
  return (ushort)r;
}
__device__ inline float b2f(ushort u) { return __uint_as_float((uint)u << 16); }

// ---------------- CSR build ----------------
__global__ void hist_kernel(const int* __restrict__ ei, int* __restrict__ cnt) {
  int e = blockIdx.x * blockDim.x + threadIdx.x;
  if (e < EE) atomicAdd(&cnt[ei[EE + e]], 1);
}

__global__ __launch_bounds__(1024) void scan_kernel(int* __restrict__ cnt_cursor,
                                                    int* __restrict__ rowptr,
                                                    float* __restrict__ invdeg) {
  __shared__ int part[1024];
  int t = threadIdx.x;
  int base = t * 4;
  int cs[4];
  int s = 0;
  for (int u = 0; u < 4; ++u) { cs[u] = cnt_cursor[base + u]; s += cs[u]; }
  part[t] = s;
  __syncthreads();
  for (int off = 1; off < 1024; off <<= 1) {
    int add = (t >= off) ? part[t - off] : 0;
    int v = part[t];
    __syncthreads();
    part[t] = v + add;
    __syncthreads();
  }
  int excl = (t > 0) ? part[t - 1] : 0;
  for (int u = 0; u < 4; ++u) {
    rowptr[base + u] = excl;
    cnt_cursor[base + u] = excl;
    invdeg[base + u] = 1.0f / (float)max(cs[u], 1);
    excl += cs[u];
  }
  if (t == 1023) rowptr[NN] = excl;
}

__global__ void fill_kernel(const int* __restrict__ ei, int* __restrict__ cursor,
                            int* __restrict__ col) {
  int e = blockIdx.x * blockDim.x + threadIdx.x;
  if (e < EE) {
    int d = ei[EE + e];
    int p = atomicAdd(&cursor[d], 1);
    col[p] = ei[e];
  }
}

// ---------------- casts ----------------
__global__ __launch_bounds__(256) void castw(const float* __restrict__ in,
                                             ushort* __restrict__ out) {
  int i4 = (blockIdx.x * 256 + threadIdx.x) * 4;
  float4 v = *(const float4*)(in + i4);
  ushort4 w;
  w.x = f2b(v.x); w.y = f2b(v.y); w.z = f2b(v.z); w.w = f2b(v.w);
  *(ushort4*)(out + i4) = w;
}

// conv weight repack: out[j][o][ks*256+ii] = w[j][o][ii][ks]
__global__ __launch_bounds__(256) void castconv(const float* __restrict__ w,
                                                ushort* __restrict__ o) {
  int idx = blockIdx.x * 256 + threadIdx.x;  // 3*256*768
  int j = idx / 196608;
  int rem = idx - j * 196608;
  int oc = rem / 768;
  int kk = rem - oc * 768;
  int ks = kk >> 8, ii = kk & 255;
  o[idx] = f2b(w[j * 196608 + oc * 768 + ii * 3 + ks]);
}

// ---------------- neighbor mean aggregation (bf16 in, fp32 acc, bf16 out) ----------------
__global__ __launch_bounds__(64) void agg_kernel(const ushort* __restrict__ hb,
                                                 const int* __restrict__ rowptr,
                                                 const int* __restrict__ col,
                                                 const float* __restrict__ invdeg,
                                                 ushort* __restrict__ aggb) {
  int n = blockIdx.x;
  int t = threadIdx.x;
  int s = rowptr[n], e = rowptr[n + 1];
  float4 acc = make_float4(0.f, 0.f, 0.f, 0.f);
  for (int j = s; j < e; ++j) {
    int c = col[j];
    ushort4 v = *(const ushort4*)(hb + (size_t)c * HH + t * 4);
    acc.x += b2f(v.x); acc.y += b2f(v.y); acc.z += b2f(v.z); acc.w += b2f(v.w);
  }
  float id = invdeg[n];
  ushort4 w;
  w.x = f2b(acc.x * id); w.y = f2b(acc.y * id);
  w.z = f2b(acc.z * id); w.w = f2b(acc.w * id);
  *(ushort4*)(aggb + (size_t)n * HH + t * 4) = w;
}

// ---------------- bf16 MFMA GEMM: C[M,Nn] = A[M,K] B[Nn,K]^T + bias ----------------
__global__ __launch_bounds__(256) void gemm_mfma(
    const ushort* __restrict__ A0, const ushort* __restrict__ A1,
    const ushort* __restrict__ B0, const ushort* __restrict__ B1,
    const float* __restrict__ bias, float* __restrict__ Cf, ushort* __restrict__ Cb,
    int M, int Nn, int K, int KHA, int KHB, int relu) {
  __shared__ ushort Alds[64][40];
  __shared__ ushort Blds[128][40];
  int t = threadIdx.x;
  int w = t >> 6, l = t & 63, quad = l >> 4, lr = l & 15;
  int wm = w & 1, wn = w >> 1;
  int m0 = blockIdx.x * 64, n0 = blockIdx.y * 128;
  int sr = t >> 2, sc8 = (t & 3) * 8;
  f32x4_t acc[2][4];
#pragma unroll
  for (int s = 0; s < 2; ++s)
#pragma unroll
    for (int q = 0; q < 4; ++q) acc[s][q] = (f32x4_t){0.f, 0.f, 0.f, 0.f};

  for (int k0 = 0; k0 < K; k0 += 32) {
    int kk = k0 + sc8;
    const ushort* ap = (kk < KHA) ? (A0 + (size_t)(m0 + sr) * KHA + kk)
                                  : (A1 + (size_t)(m0 + sr) * (K - KHA) + (kk - KHA));
    uint4 av = *(const uint4*)ap;
    const ushort* bp0 = (kk < KHB) ? (B0 + (size_t)(n0 + sr) * KHB + kk)
                                   : (B1 + (size_t)(n0 + sr) * (K - KHB) + (kk - KHB));
    uint4 bv0 = *(const uint4*)bp0;
    const ushort* bp1 = (kk < KHB) ? (B0 + (size_t)(n0 + 64 + sr) * KHB + kk)
                                   : (B1 + (size_t)(n0 + 64 + sr) * (K - KHB) + (kk - KHB));
    uint4 bv1 = *(const uint4*)bp1;
    __syncthreads();
    *(uint4*)&Alds[sr][sc8] = av;
    *(uint4*)&Blds[sr][sc8] = bv0;
    *(uint4*)&Blds[64 + sr][sc8] = bv1;
    __syncthreads();
    bf16x8_t af[2], bf[4];
#pragma unroll
    for (int s = 0; s < 2; ++s)
      af[s] = *(const bf16x8_t*)&Alds[wm * 32 + s * 16 + lr][quad * 8];
#pragma unroll
    for (int q = 0; q < 4; ++q)
      bf[q] = *(const bf16x8_t*)&Blds[wn * 64 + q * 16 + lr][quad * 8];
#pragma unroll
    for (int s = 0; s < 2; ++s)
#pragma unroll
      for (int q = 0; q < 4; ++q)
        acc[s][q] = __builtin_amdgcn_mfma_f32_16x16x32_bf16(af[s], bf[q], acc[s][q], 0, 0, 0);
  }
#pragma unroll
  for (int s = 0; s < 2; ++s) {
#pragma unroll
    for (int q = 0; q < 4; ++q) {
      int n = n0 + wn * 64 + q * 16 + lr;
      float bb = bias[n];
#pragma unroll
      for (int r = 0; r < 4; ++r) {
        int m = m0 + wm * 32 + s * 16 + quad * 4 + r;
        float v = acc[s][q][r] + bb;
        if (relu) v = fmaxf(v, 0.f);
        if (Cf) Cf[(size_t)m * Nn + n] = v;
        if (Cb) Cb[(size_t)m * Nn + n] = f2b(v);
      }
    }
  }
}

// ---------------- dual independent 256x256 GEMMs (SAGE layer), z picks operand set ----------------
__global__ __launch_bounds__(256) void gemm_dual(
    const ushort* __restrict__ A0, const ushort* __restrict__ B0,
    const float* __restrict__ bias0, float* __restrict__ C0,
    const ushort* __restrict__ A1, const ushort* __restrict__ B1,
    float* __restrict__ C1) {
  __shared__ ushort Alds[64][40];
  __shared__ ushort Blds[128][40];
  int t = threadIdx.x;
  int w = t >> 6, l = t & 63, quad = l >> 4, lr = l & 15;
  int wm = w & 1, wn = w >> 1;
  int m0 = blockIdx.x * 64, n0 = blockIdx.y * 128;
  int z = blockIdx.z;
  const ushort* A = z ? A1 : A0;
  const ushort* B = z ? B1 : B0;
  float* C = z ? C1 : C0;
  int sr = t >> 2, sc8 = (t & 3) * 8;
  f32x4_t acc[2][4];
#pragma unroll
  for (int s = 0; s < 2; ++s)
#pragma unroll
    for (int q = 0; q < 4; ++q) acc[s][q] = (f32x4_t){0.f, 0.f, 0.f, 0.f};

  for (int k0 = 0; k0 < 256; k0 += 32) {
    int kk = k0 + sc8;
    uint4 av = *(const uint4*)(A + (size_t)(m0 + sr) * 256 + kk);
    uint4 bv0 = *(const uint4*)(B + (size_t)(n0 + sr) * 256 + kk);
    uint4 bv1 = *(const uint4*)(B + (size_t)(n0 + 64 + sr) * 256 + kk);
    __syncthreads();
    *(uint4*)&Alds[sr][sc8] = av;
    *(uint4*)&Blds[sr][sc8] = bv0;
    *(uint4*)&Blds[64 + sr][sc8] = bv1;
    __syncthreads();
    bf16x8_t af[2], bf[4];
#pragma unroll
    for (int s = 0; s < 2; ++s)
      af[s] = *(const bf16x8_t*)&Alds[wm * 32 + s * 16 + lr][quad * 8];
#pragma unroll
    for (int q = 0; q < 4; ++q)
      bf[q] = *(const bf16x8_t*)&Blds[wn * 64 + q * 16 + lr][quad * 8];
#pragma unroll
    for (int s = 0; s < 2; ++s)
#pragma unroll
      for (int q = 0; q < 4; ++q)
        acc[s][q] = __builtin_amdgcn_mfma_f32_16x16x32_bf16(af[s], bf[q], acc[s][q], 0, 0, 0);
  }
#pragma unroll
  for (int s = 0; s < 2; ++s) {
#pragma unroll
    for (int q = 0; q < 4; ++q) {
      int n = n0 + wn * 64 + q * 16 + lr;
      float bb = z ? 0.f : bias0[n];
#pragma unroll
      for (int r = 0; r < 4; ++r) {
        int m = m0 + wm * 32 + s * 16 + quad * 4 + r;
        C[(size_t)m * 256 + n] = acc[s][q][r] + bb;
      }
    }
  }
}

// ---------------- conv1d(k=3,pad=1) as MFMA GEMM, z-split K (2x384), raw fp32 out ----------------
__global__ __launch_bounds__(256) void gemm_conv_mfma(
    const ushort* __restrict__ Ab, const ushort* __restrict__ B,
    const float* __restrict__ bias, float* __restrict__ C0, float* __restrict__ C1) {
  __shared__ ushort Alds[64][40];
  __shared__ ushort Blds[128][40];
  int t = threadIdx.x;
  int w = t >> 6, l = t & 63, quad = l >> 4, lr = l & 15;
  int wm = w & 1, wn = w >> 1;
  int m0 = blockIdx.x * 64, n0 = blockIdx.y * 128;
  int z = blockIdx.z;
  float* C = z ? C1 : C0;
  int sr = t >> 2, sc8 = (t & 3) * 8;
  f32x4_t acc[2][4];
#pragma unroll
  for (int s = 0; s < 2; ++s)
#pragma unroll
    for (int q = 0; q < 4; ++q) acc[s][q] = (f32x4_t){0.f, 0.f, 0.f, 0.f};

  for (int k0 = 0; k0 < 384; k0 += 32) {
    int kk = z * 384 + k0 + sc8;
    int ks = kk >> 8, ii = kk & 255;
    int nr = m0 + sr + ks - 1;
    uint4 av = make_uint4(0u, 0u, 0u, 0u);
    if (nr >= 0 && nr < NN) av = *(const uint4*)(Ab + (size_t)nr * HH + ii);
    uint4 bv0 = *(const uint4*)(B + (size_t)(n0 + sr) * 768 + kk);
    uint4 bv1 = *(const uint4*)(B + (size_t)(n0 + 64 + sr) * 768 + kk);
    __syncthreads();
    *(uint4*)&Alds[sr][sc8] = av;
    *(uint4*)&Blds[sr][sc8] = bv0;
    *(uint4*)&Blds[64 + sr][sc8] = bv1;
    __syncthreads();
    bf16x8_t af[2], bf[4];
#pragma unroll
    for (int s = 0; s < 2; ++s)
      af[s] = *(const bf16x8_t*)&Alds[wm * 32 + s * 16 + lr][quad * 8];
#pragma unroll
    for (int q = 0; q < 4; ++q)
      bf[q] = *(const bf16x8_t*)&Blds[wn * 64 + q * 16 + lr][quad * 8];
#pragma unroll
    for (int s = 0; s < 2; ++s)
#pragma unroll
      for (int q = 0; q < 4; ++q)
        acc[s][q] = __builtin_amdgcn_mfma_f32_16x16x32_bf16(af[s], bf[q], acc[s][q], 0, 0, 0);
  }
#pragma unroll
  for (int s = 0; s < 2; ++s) {
#pragma unroll
    for (int q = 0; q < 4; ++q) {
      int n = n0 + wn * 64 + q * 16 + lr;
      float bb = z ? 0.f : bias[n];
#pragma unroll
      for (int r = 0; r < 4; ++r) {
        int m = m0 + wm * 32 + s * 16 + quad * 4 + r;
        C[(size_t)m * HH + n] = acc[s][q][r] + bb;
      }
    }
  }
}

// ---------------- fp32 tiled GEMM (fuse head only) ----------------
__global__ __launch_bounds__(256) void gemm_std(
    const float* __restrict__ A0, const float* __restrict__ B0,
    const float* __restrict__ bias, float* __restrict__ C,
    int M, int Nn, int K) {
  __shared__ float As[16][68];
  __shared__ float Bs[16][68];
  int t = threadIdx.x;
  int m0 = blockIdx.x * 64, n0 = blockIdx.y * 64;
  int ty = t >> 4, tx = t & 15;
  int lr = t >> 2, lc4 = (t & 3) * 4;
  float acc[4][4] = {};
  for (int k0 = 0; k0 < K; k0 += 16) {
    int kk = k0 + lc4;
    float4 va = *(const float4*)(A0 + (size_t)(m0 + lr) * K + kk);
    As[lc4 + 0][lr] = va.x; As[lc4 + 1][lr] = va.y;
    As[lc4 + 2][lr] = va.z; As[lc4 + 3][lr] = va.w;
    float4 vb = *(const float4*)(B0 + (size_t)(n0 + lr) * K + kk);
    Bs[lc4 + 0][lr] = vb.x; Bs[lc4 + 1][lr] = vb.y;
    Bs[lc4 + 2][lr] = vb.z; Bs[lc4 + 3][lr] = vb.w;
    __syncthreads();
#pragma unroll
    for (int k = 0; k < 16; ++k) {
      float4 a4 = *(const float4*)&As[k][4 * ty];
      float4 b4 = *(const float4*)&Bs[k][4 * tx];
      float av[4] = {a4.x, a4.y, a4.z, a4.w};
      float bv[4] = {b4.x, b4.y, b4.z, b4.w};
#pragma unroll
      for (int i = 0; i < 4; ++i)
#pragma unroll
        for (int j = 0; j < 4; ++j) acc[i][j] += av[i] * bv[j];
    }
    __syncthreads();
  }
#pragma unroll
  for (int i = 0; i < 4; ++i) {
    int m = m0 + 4 * ty + i;
    float o[4];
#pragma unroll
    for (int j = 0; j < 4; ++j) o[j] = acc[i][j] + bias[n0 + 4 * tx + j];
    float4 o4 = make_float4(o[0], o[1], o[2], o[3]);
    *(float4*)(C + (size_t)m * Nn + n0 + 4 * tx) = o4;
  }
}

// ---------------- fused LayerNorm (+ x2 sum + pre-relu + optional relu+residual) ----------------
__global__ __launch_bounds__(256) void ln_fuse(
    const float* __restrict__ x, const float* __restrict__ x2,
    const float* __restrict__ g, const float* __restrict__ b,
    const float* __restrict__ res, float* __restrict__ outf, ushort* __restrict__ outb,
    int D, int do_ln, int relu_res, int prerelu) {
  int row = blockIdx.x, t = threadIdx.x;
  int nv = D >> 8;
  float vals[2];
  float s = 0.f, sq = 0.f;
  for (int u = 0; u < nv; ++u) {
    int c = t + (u << 8);
    float v = x[(size_t)row * D + c];
    if (x2) v += x2[(size_t)row * D + c];
    if (prerelu) v = fmaxf(v, 0.f);
    vals[u] = v; s += v; sq += v * v;
  }
  __shared__ float red[8];
  float m = 0.f, inv = 1.f;
  if (do_ln) {
    for (int off = 32; off >= 1; off >>= 1) {
      s += __shfl_xor(s, off);
      sq += __shfl_xor(sq, off);
    }
    int wid = t >> 6;
    if ((t & 63) == 0) { red[wid] = s; red[4 + wid] = sq; }
    __syncthreads();
    if (t == 0) {
      float S = red[0] + red[1] + red[2] + red[3];
      float Q = red[4] + red[5] + red[6] + red[7];
      float mm = S / D;
      float vv = Q / D - mm * mm;
      red[0] = mm;
      red[1] = rsqrtf(vv + LN_EPS);
    }
    __syncthreads();
    m = red[0]; inv = red[1];
  }
  for (int u = 0; u < nv; ++u) {
    int c = t + (u << 8);
    float y = vals[u];
    if (do_ln) y = (y - m) * inv * g[c] + b[c];
    if (relu_res) y = fmaxf(y, 0.f) + res[(size_t)row * D + c];
    if (outf) outf[(size_t)row * D + c] = y;
    if (outb) outb[(size_t)row * D + c] = f2b(y);
  }
}

// ---------------- K/V repack for fragment-direct attention ----------------
// Kt[head][kt][ks][key32][elem32]: fragment (ks,ct) for tile kt = 1KB contiguous.
// VtT[head][kt][d128][key32]: fragment (dt) for tile kt = 1KB contiguous.
__global__ __launch_bounds__(256) void kvpack(const ushort* __restrict__ qkvb,
                                              ushort* __restrict__ Kt,
                                              ushort* __restrict__ VtT) {
  int t = threadIdx.x;
  int n0 = blockIdx.x * 32;  // 32 global keys
  int by = blockIdx.y;       // 0..15
  int kt = n0 >> 5;
  // K repack: cols 512 + by*32 .. +31  (head = by>>2, ks = by&3)
  {
    int head = by >> 2, ks = by & 3;
    int key = t >> 3, e4 = (t & 7) * 4;
    uint2 v = *(const uint2*)(qkvb + (size_t)(n0 + key) * 1536 + 512 + head * 128 + ks * 32 + e4);
    *(uint2*)(Kt + ((((size_t)head * 128 + kt) * 4 + ks) * 32 + key) * 32 + e4) = v;
  }
  // V transpose: cols 1024 + by*32 .. +31
  __shared__ ushort tile[32][34];
  int d0 = by * 32;
  int tx = t & 31, ty = t >> 5;
#pragma unroll
  for (int u = 0; u < 4; ++u) {
    int r = ty + 8 * u;
    tile[r][tx] = qkvb[(size_t)(n0 + r) * 1536 + 1024 + d0 + tx];
  }
  __syncthreads();
#pragma unroll
  for (int u = 0; u < 4; ++u) {
    int dg = d0 + ty + 8 * u;
    int head = dg >> 7, dl = dg & 127;
    VtT[((((size_t)head * 128 + kt) * 128 + dl) << 5) + tx] = tile[tx][ty + 8 * u];
  }
}

// ---------------- bf16 MFMA flash attention (4 heads, hd=128), bf16 out ----------------
// v6 = v5 with the spill fixed. 16 waves = 2 q-halves x 8 k-eighths; 64 q-rows/block.
// CRITICAL: LDS padded to 82 KB so only ONE 1024-thread block fits per CU. With two
// blocks possible (v5, 72KB), the compiler targeted 8 waves/SIMD and capped VGPR at 64
// -> 500MB of scratch spill (measured). At 1 block/CU the budget is 128 VGPR, which
// this wave body fits spill-free (proven by R4 at VGPR_Count=128).
__global__ __launch_bounds__(1024, 4) void attn_mfma(const ushort* __restrict__ qkvb,
                                                     const ushort* __restrict__ Kt,
                                                     const ushort* __restrict__ VtT,
                                                     ushort* __restrict__ Ob) {
  // loop phase: P[16][32][40] ushort (40.0 KB, wave-private slices, overlays OS)
  // merge phase: OS[16][32][34] f32 (69632 B) + Dsum[16][32] (2 KB) + invd[64] (256 B)
  // padded to 83968 B to force 1 block/CU (see header comment)
  __shared__ __align__(16) char smem[83968];
  int t = threadIdx.x;
  int w = t >> 6, l = t & 63;
  int quad = l >> 4, lr = l & 15;
  int qh = w >> 3, ke = w & 7;
  int head = blockIdx.y;
  int q0 = blockIdx.x * 64 + qh * 32;

  ushort* Pl = (ushort*)smem + w * 1280;  // [32][40] wave-private

  bf16x8_t qf[2][4];
#pragma unroll
  for (int s = 0; s < 2; ++s)
#pragma unroll
    for (int ks = 0; ks < 4; ++ks)
      qf[s][ks] = *(const bf16x8_t*)(qkvb + (size_t)(q0 + s * 16 + lr) * 1536 +
                                     head * 128 + ks * 32 + quad * 8);

  f32x4_t of[2][8];
#pragma unroll
  for (int s = 0; s < 2; ++s)
#pragma unroll
    for (int dt = 0; dt < 8; ++dt) of[s][dt] = (f32x4_t){0.f, 0.f, 0.f, 0.f};
  float den[2][4] = {{0.f, 0.f, 0.f, 0.f}, {0.f, 0.f, 0.f, 0.f}};

  const int lnoff = lr * 32 + quad * 8;  // lane offset within a 1KB fragment
  const int tile0 = ke * 16;             // this wave's k-eighth (16 tiles of 32 keys)

  for (int tt = 0; tt < 16; ++tt) {
    int kt = tile0 + tt;
    const ushort* kbase = Kt + (((size_t)head * 128 + kt) << 12);
    const ushort* vbase = VtT + (((size_t)head * 128 + kt) << 12);

    // K fragments
    bf16x8_t kf[4][2];
#pragma unroll
    for (int ks = 0; ks < 4; ++ks)
#pragma unroll
      for (int ct = 0; ct < 2; ++ct)
        kf[ks][ct] = *(const bf16x8_t*)(kbase + ks * 1024 + ct * 512 + lnoff);
    // V fragments issued early (consumed after QK+exp: latency hides under them)
    bf16x8_t vf[8];
#pragma unroll
    for (int dt = 0; dt < 8; ++dt)
      vf[dt] = *(const bf16x8_t*)(vbase + dt * 512 + lnoff);

    // QK^T: S[32 q-rows][32 keys]
    f32x4_t sf[2][2];
#pragma unroll
    for (int s = 0; s < 2; ++s)
#pragma unroll
      for (int ct = 0; ct < 2; ++ct) sf[s][ct] = (f32x4_t){0.f, 0.f, 0.f, 0.f};
    __builtin_amdgcn_s_setprio(1);
#pragma unroll
    for (int ks = 0; ks < 4; ++ks)
#pragma unroll
      for (int ct = 0; ct < 2; ++ct)
#pragma unroll
        for (int s = 0; s < 2; ++s)
          sf[s][ct] = __builtin_amdgcn_mfma_f32_16x16x32_bf16(qf[s][ks], kf[ks][ct], sf[s][ct], 0, 0, 0);
    __builtin_amdgcn_s_setprio(0);

    // softmax exp (fixed shift), P -> wave-private LDS, per-lane den partials
#pragma unroll
    for (int s = 0; s < 2; ++s)
#pragma unroll
      for (int ct = 0; ct < 2; ++ct)
#pragma unroll
        for (int r = 0; r < 4; ++r) {
          float e = __expf(sf[s][ct][r] * ATT_SCALE - ATT_SHIFT);
          Pl[(s * 16 + quad * 4 + r) * 40 + ct * 16 + lr] = f2b(e);
          den[s][r] += e;
        }

    // PV: O[32 rows][128 d] += P[32][32] * V[32][128]
    __builtin_amdgcn_s_setprio(1);
#pragma unroll
    for (int s = 0; s < 2; ++s) {
      bf16x8_t pf = *(const bf16x8_t*)&Pl[(s * 16 + lr) * 40 + quad * 8];
#pragma unroll
      for (int dt = 0; dt < 8; ++dt)
        of[s][dt] = __builtin_amdgcn_mfma_f32_16x16x32_bf16(pf, vf[dt], of[s][dt], 0, 0, 0);
    }
    __builtin_amdgcn_s_setprio(0);
  }

  // finish den: reduce over the 16 lr lanes (per row s*16+quad*4+r)
#pragma unroll
  for (int mask = 1; mask < 16; mask <<= 1)
#pragma unroll
    for (int s = 0; s < 2; ++s)
#pragma unroll
      for (int r = 0; r < 4; ++r) den[s][r] += __shfl_xor(den[s][r], mask);

  // ---- merge the 8 k-partials per q-half (pure addition: fixed-shift softmax) ----
  __syncthreads();  // all waves' loops done; P region dead; safe to overlay OS
  float* OS   = (float*)smem;             // [16][32][34]
  float* Dsum = (float*)(smem + 69632);   // [16][32]
  float* invd = (float*)(smem + 71680);   // [64]
  if (lr == 0) {
#pragma unroll
    for (int s = 0; s < 2; ++s)
#pragma unroll
      for (int r = 0; r < 4; ++r) Dsum[w * 32 + s * 16 + quad * 4 + r] = den[s][r];
  }
  __syncthreads();
  if (t < 64) {
    int oh = t >> 5, row = t & 31;
    float sden = 0.f;
#pragma unroll
    for (int j = 0; j < 8; ++j) sden += Dsum[(oh * 8 + j) * 32 + row];
    invd[t] = 1.0f / sden;
  }
  // O merge in 4 chunks of 32 columns (2 dt each); OS reused per chunk
  for (int dc = 0; dc < 4; ++dc) {
#pragma unroll
    for (int s = 0; s < 2; ++s)
#pragma unroll
      for (int u = 0; u < 2; ++u) {
        int dt = dc * 2 + u;
#pragma unroll
        for (int r = 0; r < 4; ++r)
          OS[w * 1088 + (s * 16 + quad * 4 + r) * 34 + u * 16 + lr] = of[s][dt][r];
      }
    __syncthreads();  // (also publishes invd on first iteration)
#pragma unroll
    for (int it = 0; it < 2; ++it) {
      int idx = t + it * 1024;
      int orow = idx >> 5, c2 = idx & 31;
      int oh = orow >> 5, row = orow & 31;
      float sum = 0.f;
#pragma unroll
      for (int j = 0; j < 8; ++j) sum += OS[(oh * 8 + j) * 1088 + row * 34 + c2];
      Ob[(size_t)(blockIdx.x * 64 + orow) * 512 + head * 128 + dc * 32 + c2] =
          f2b(sum * invd[orow]);
    }
    __syncthreads();
  }
}

// ---------------- launch ----------------
extern "C" void kernel_launch(void* const* d_in, const int* in_sizes, int n_in,
                              void* d_out, int out_size, void* d_ws, size_t ws_size,
                              hipStream_t stream) {
  const float* x          = (const float*)d_in[0];
  const int*   ei         = (const int*)d_in[1];
  const float* sage_wl    = (const float*)d_in[2];
  const float* sage_wr    = (const float*)d_in[3];
  const float* sage_bl    = (const float*)d_in[4];
  const float* ln_g       = (const float*)d_in[5];
  const float* ln_b       = (const float*)d_in[6];
  const float* conv_w     = (const float*)d_in[7];
  const float* conv_b     = (const float*)d_in[8];
  const float* cnorm_g    = (const float*)d_in[9];
  const float* cnorm_b    = (const float*)d_in[10];
  const float* in_proj_w  = (const float*)d_in[11];
  const float* in_proj_b  = (const float*)d_in[12];
  const float* out_proj_w = (const float*)d_in[13];
  const float* out_proj_b = (const float*)d_in[14];
  const float* anorm_g    = (const float*)d_in[15];
  const float* anorm_b    = (const float*)d_in[16];
  const float* fuse_w     = (const float*)d_in[17];
  const float* fuse_b     = (const float*)d_in[18];
  float* out = (float*)d_out;

  char* ws = (char*)d_ws;
  const size_t MB = 1 << 20;
  int*    rowptr = (int*)(ws + 0);
  int*    cnt    = (int*)(ws + 65536);
  int*    col    = (int*)(ws + 131072);
  float*  invdeg = (float*)(ws + 786432);
  float*  h    = (float*)(ws + 1 * MB);
  ushort* hb   = (ushort*)(ws + 5 * MB);
  ushort* aggb = (ushort*)(ws + 7 * MB);
  float*  tmp  = (float*)(ws + 9 * MB);
  ushort* c0b  = (ushort*)(ws + 13 * MB);
  ushort* c1b  = (ushort*)(ws + 15 * MB);
  ushort* qkvb = (ushort*)(ws + 17 * MB);
  float*  op   = (float*)(ws + 17 * MB);    // reuses qkvb after attention
  float*  tmp2 = (float*)(ws + 25 * MB);    // split-K partial (qkvb tail, dead pre-in_proj)
  ushort* Kt   = (ushort*)(ws + 1 * MB);    // reuses h (dead after GNN): 4MB
  ushort* Vt   = (ushort*)(ws + 29 * MB);   // VtT tile-major V (4MB)
  ushort* aob  = (ushort*)(ws + 33 * MB);
  ushort* wlb  = (ushort*)(ws + 37 * MB);            // 6*256*256 = 786KB
  ushort* wrb  = (ushort*)(ws + 37 * MB + 786432);   // 786KB
  ushort* cvb  = (ushort*)(ws + 37 * MB + 1572864);  // 3*256*768 = 1.125MB
  ushort* ipb  = (ushort*)(ws + 37 * MB + 2752512);  // 1536*512 = 1.5MB
  ushort* opb  = (ushort*)(ws + 37 * MB + 4325376);  // 512*512 = 0.5MB

  // weight casts
  castw<<<(6 * 256 * 256) / 1024, 256, 0, stream>>>(sage_wl, wlb);
  castw<<<(6 * 256 * 256) / 1024, 256, 0, stream>>>(sage_wr, wrb);
  castconv<<<(3 * 256 * 768) / 256, 256, 0, stream>>>(conv_w, cvb);
  castw<<<(1536 * 512) / 1024, 256, 0, stream>>>(in_proj_w, ipb);
  castw<<<(512 * 512) / 1024, 256, 0, stream>>>(out_proj_w, opb);

  // CSR
  hipMemsetAsync(cnt, 0, NN * sizeof(int), stream);
  hist_kernel<<<EE / 256, 256, 0, stream>>>(ei, cnt);
  scan_kernel<<<1, 1024, 0, stream>>>(cnt, rowptr, invdeg);
  fill_kernel<<<EE / 256, 256, 0, stream>>>(ei, cnt, col);
  hipMemcpyAsync(h, x, (size_t)NN * HH * sizeof(float), hipMemcpyDeviceToDevice, stream);
  castw<<<(NN * HH) / 1024, 256, 0, stream>>>(x, hb);

  // GNN: 6 SAGE layers (z-split: z=0 agg@wl^T+bias -> tmp, z=1 h@wr^T -> tmp2)
  for (int i = 0; i < 6; ++i) {
    agg_kernel<<<NN, 64, 0, stream>>>(hb, rowptr, col, invdeg, aggb);
    gemm_dual<<<dim3(64, 2, 2), 256, 0, stream>>>(
        aggb, wlb + (size_t)i * HH * HH, sage_bl + i * HH, tmp,
        hb, wrb + (size_t)i * HH * HH, tmp2);
    int do_ln = (i < 5) ? 1 : 0;
    const float* gp = do_ln ? (ln_g + i * HH) : ln_g;
    const float* bp = do_ln ? (ln_b + i * HH) : ln_b;
    ln_fuse<<<NN, 256, 0, stream>>>(tmp, tmp2, gp, bp, h, h, hb, HH, do_ln, 1, 0);
  }

  // CNN: 3 conv layers (z-split K: 2x384; combiner does relu(sum+bias) then LN)
  const ushort* cin = hb;
  ushort* couts[3] = {c0b, c1b, c0b};
  for (int j = 0; j < 3; ++j) {
    gemm_conv_mfma<<<dim3(64, 2, 2), 256, 0, stream>>>(
        cin, cvb + (size_t)j * HH * 768, conv_b + j * HH, tmp, tmp2);
    ln_fuse<<<NN, 256, 0, stream>>>(tmp, tmp2, cnorm_g + j * HH, cnorm_b + j * HH,
                                    nullptr, nullptr, couts[j], HH, 1, 0, 1);
    cin = couts[j];
  }

  // attention
  gemm_mfma<<<dim3(64, 12), 256, 0, stream>>>(
      hb, c0b, ipb, nullptr, in_proj_b, nullptr, qkvb, NN, 1536, 512, 256, 1536 * 0 + 512, 0);
  kvpack<<<dim3(NN / 32, 16), 256, 0, stream>>>(qkvb, Kt, Vt);
  attn_mfma<<<dim3(64, 4), 1024, 0, stream>>>(qkvb, Kt, Vt, aob);

  gemm_mfma<<<dim3(64, 4), 256, 0, stream>>>(
      aob, nullptr, opb, nullptr, out_proj_b, op, nullptr, NN, 512, 512, 512, 512, 0);
  ln_fuse<<<NN, 256, 0, stream>>>(op, nullptr, anorm_g, anorm_b, nullptr, op, nullptr, 512, 1, 0, 0);
  gemm_std<<<dim3(64, 1), 256, 0, stream>>>(op, fuse_w, fuse_b, out, NN, 64, 512);
}

// Round 7
// 692.793 us; speedup vs baseline: 1.0468x; 1.0421x over previous
//
#include <hip/hip_runtime.h>

#define NN 4096
#define HH 256
#define EE 131072

__device__ __constant__ float LN_EPS = 1e-5f;
#define ATT_SCALE 0.08838834764831845f
#define ATT_SHIFT 30.0f

typedef __attribute__((ext_vector_type(8))) short bf16x8_t;
typedef __attribute__((ext_vector_type(4))) float f32x4_t;

__device__ inline ushort f2b(float f) {
  uint u = __float_as_uint(f);
  uint r = (u + 0x7FFF + ((u >> 16) & 1)) >> 16;
  return (ushort)r;
}
__device__ inline float b2f(ushort u) { return __uint_as_float((uint)u << 16); }

// ---------------- CSR build ----------------
__global__ void hist_kernel(const int* __restrict__ ei, int* __restrict__ cnt) {
  int e = blockIdx.x * blockDim.x + threadIdx.x;
  if (e < EE) atomicAdd(&cnt[ei[EE + e]], 1);
}

__global__ __launch_bounds__(1024) void scan_kernel(int* __restrict__ cnt_cursor,
                                                    int* __restrict__ rowptr,
                                                    float* __restrict__ invdeg) {
  __shared__ int part[1024];
  int t = threadIdx.x;
  int base = t * 4;
  int cs[4];
  int s = 0;
  for (int u = 0; u < 4; ++u) { cs[u] = cnt_cursor[base + u]; s += cs[u]; }
  part[t] = s;
  __syncthreads();
  for (int off = 1; off < 1024; off <<= 1) {
    int add = (t >= off) ? part[t - off] : 0;
    int v = part[t];
    __syncthreads();
    part[t] = v + add;
    __syncthreads();
  }
  int excl = (t > 0) ? part[t - 1] : 0;
  for (int u = 0; u < 4; ++u) {
    rowptr[base + u] = excl;
    cnt_cursor[base + u] = excl;
    invdeg[base + u] = 1.0f / (float)max(cs[u], 1);
    excl += cs[u];
  }
  if (t == 1023) rowptr[NN] = excl;
}

__global__ void fill_kernel(const int* __restrict__ ei, int* __restrict__ cursor,
                            int* __restrict__ col) {
  int e = blockIdx.x * blockDim.x + threadIdx.x;
  if (e < EE) {
    int d = ei[EE + e];
    int p = atomicAdd(&cursor[d], 1);
    col[p] = ei[e];
  }
}

// ---------------- all weight casts in ONE launch ----------------
// quad ranges (x4 elems): wl 0..393216, wr ..786432, conv ..1376256 (transform),
// ip ..2162688, op ..2424832
__global__ __launch_bounds__(256) void castall(
    const float* __restrict__ wl, const float* __restrict__ wr,
    const float* __restrict__ cw, const float* __restrict__ ip,
    const float* __restrict__ opw,
    ushort* __restrict__ wlb, ushort* __restrict__ wrb, ushort* __restrict__ cvb,
    ushort* __restrict__ ipb, ushort* __restrict__ opb) {
  int i4 = (blockIdx.x * 256 + threadIdx.x) * 4;
  if (i4 >= 2424832) return;
  ushort4 o;
  if (i4 < 393216) {
    float4 v = *(const float4*)(wl + i4);
    o.x = f2b(v.x); o.y = f2b(v.y); o.z = f2b(v.z); o.w = f2b(v.w);
    *(ushort4*)(wlb + i4) = o;
  } else if (i4 < 786432) {
    int p = i4 - 393216;
    float4 v = *(const float4*)(wr + p);
    o.x = f2b(v.x); o.y = f2b(v.y); o.z = f2b(v.z); o.w = f2b(v.w);
    *(ushort4*)(wrb + p) = o;
  } else if (i4 < 1376256) {
    int p = i4 - 786432;
    ushort tmp[4];
#pragma unroll
    for (int u = 0; u < 4; ++u) {
      int idx = p + u;
      int j = idx / 196608;
      int rem = idx - j * 196608;
      int oc = rem / 768;
      int kk = rem - oc * 768;
      int ks = kk >> 8, ii = kk & 255;
      tmp[u] = f2b(cw[j * 196608 + oc * 768 + ii * 3 + ks]);
    }
    o.x = tmp[0]; o.y = tmp[1]; o.z = tmp[2]; o.w = tmp[3];
    *(ushort4*)(cvb + p) = o;
  } else if (i4 < 2162688) {
    int p = i4 - 1376256;
    float4 v = *(const float4*)(ip + p);
    o.x = f2b(v.x); o.y = f2b(v.y); o.z = f2b(v.z); o.w = f2b(v.w);
    *(ushort4*)(ipb + p) = o;
  } else {
    int p = i4 - 2162688;
    float4 v = *(const float4*)(opw + p);
    o.x = f2b(v.x); o.y = f2b(v.y); o.z = f2b(v.z); o.w = f2b(v.w);
    *(ushort4*)(opb + p) = o;
  }
}

// ---------------- x -> h (fp32 copy) + hb (bf16) in one launch ----------------
__global__ __launch_bounds__(256) void copycast(const float* __restrict__ x,
                                                float* __restrict__ h,
                                                ushort* __restrict__ hb) {
  int i4 = (blockIdx.x * 256 + threadIdx.x) * 4;
  float4 v = *(const float4*)(x + i4);
  *(float4*)(h + i4) = v;
  ushort4 w;
  w.x = f2b(v.x); w.y = f2b(v.y); w.z = f2b(v.z); w.w = f2b(v.w);
  *(ushort4*)(hb + i4) = w;
}

// ---------------- neighbor mean aggregation (bf16 in, fp32 acc, bf16 out) ----------------
__global__ __launch_bounds__(64) void agg_kernel(const ushort* __restrict__ hb,
                                                 const int* __restrict__ rowptr,
                                                 const int* __restrict__ col,
                                                 const float* __restrict__ invdeg,
                                                 ushort* __restrict__ aggb) {
  int n = blockIdx.x;
  int t = threadIdx.x;
  int s = rowptr[n], e = rowptr[n + 1];
  float4 acc = make_float4(0.f, 0.f, 0.f, 0.f);
  for (int j = s; j < e; ++j) {
    int c = col[j];
    ushort4 v = *(const ushort4*)(hb + (size_t)c * HH + t * 4);
    acc.x += b2f(v.x); acc.y += b2f(v.y); acc.z += b2f(v.z); acc.w += b2f(v.w);
  }
  float id = invdeg[n];
  ushort4 w;
  w.x = f2b(acc.x * id); w.y = f2b(acc.y * id);
  w.z = f2b(acc.z * id); w.w = f2b(acc.w * id);
  *(ushort4*)(aggb + (size_t)n * HH + t * 4) = w;
}

// ---------------- bf16 MFMA GEMM: C[M,Nn] = A[M,K] B[Nn,K]^T + bias ----------------
__global__ __launch_bounds__(256) void gemm_mfma(
    const ushort* __restrict__ A0, const ushort* __restrict__ A1,
    const ushort* __restrict__ B0, const ushort* __restrict__ B1,
    const float* __restrict__ bias, float* __restrict__ Cf, ushort* __restrict__ Cb,
    int M, int Nn, int K, int KHA, int KHB, int relu) {
  __shared__ ushort Alds[64][40];
  __shared__ ushort Blds[128][40];
  int t = threadIdx.x;
  int w = t >> 6, l = t & 63, quad = l >> 4, lr = l & 15;
  int wm = w & 1, wn = w >> 1;
  int m0 = blockIdx.x * 64, n0 = blockIdx.y * 128;
  int sr = t >> 2, sc8 = (t & 3) * 8;
  f32x4_t acc[2][4];
#pragma unroll
  for (int s = 0; s < 2; ++s)
#pragma unroll
    for (int q = 0; q < 4; ++q) acc[s][q] = (f32x4_t){0.f, 0.f, 0.f, 0.f};

  for (int k0 = 0; k0 < K; k0 += 32) {
    int kk = k0 + sc8;
    const ushort* ap = (kk < KHA) ? (A0 + (size_t)(m0 + sr) * KHA + kk)
                                  : (A1 + (size_t)(m0 + sr) * (K - KHA) + (kk - KHA));
    uint4 av = *(const uint4*)ap;
    const ushort* bp0 = (kk < KHB) ? (B0 + (size_t)(n0 + sr) * KHB + kk)
                                   : (B1 + (size_t)(n0 + sr) * (K - KHB) + (kk - KHB));
    uint4 bv0 = *(const uint4*)bp0;
    const ushort* bp1 = (kk < KHB) ? (B0 + (size_t)(n0 + 64 + sr) * KHB + kk)
                                   : (B1 + (size_t)(n0 + 64 + sr) * (K - KHB) + (kk - KHB));
    uint4 bv1 = *(const uint4*)bp1;
    __syncthreads();
    *(uint4*)&Alds[sr][sc8] = av;
    *(uint4*)&Blds[sr][sc8] = bv0;
    *(uint4*)&Blds[64 + sr][sc8] = bv1;
    __syncthreads();
    bf16x8_t af[2], bf[4];
#pragma unroll
    for (int s = 0; s < 2; ++s)
      af[s] = *(const bf16x8_t*)&Alds[wm * 32 + s * 16 + lr][quad * 8];
#pragma unroll
    for (int q = 0; q < 4; ++q)
      bf[q] = *(const bf16x8_t*)&Blds[wn * 64 + q * 16 + lr][quad * 8];
#pragma unroll
    for (int s = 0; s < 2; ++s)
#pragma unroll
      for (int q = 0; q < 4; ++q)
        acc[s][q] = __builtin_amdgcn_mfma_f32_16x16x32_bf16(af[s], bf[q], acc[s][q], 0, 0, 0);
  }
#pragma unroll
  for (int s = 0; s < 2; ++s) {
#pragma unroll
    for (int q = 0; q < 4; ++q) {
      int n = n0 + wn * 64 + q * 16 + lr;
      float bb = bias[n];
#pragma unroll
      for (int r = 0; r < 4; ++r) {
        int m = m0 + wm * 32 + s * 16 + quad * 4 + r;
        float v = acc[s][q][r] + bb;
        if (relu) v = fmaxf(v, 0.f);
        if (Cf) Cf[(size_t)m * Nn + n] = v;
        if (Cb) Cb[(size_t)m * Nn + n] = f2b(v);
      }
    }
  }
}

// ---------------- SAGE layer fully fused: GEMM(K=512 concat) + bias + LN + relu + residual ----------------
// BM=32, BN=256 (full rows per block) -> block-wide LN in epilogue. 128 blocks, 4 waves.
// t_out = A0@B0^T + bias + A1@B1^T ; y = do_ln ? LN(t)*g+b : t ; y = relu(y)+h ; h=y, hb=bf16(y)
__global__ __launch_bounds__(256) void sage_fused(
    const ushort* __restrict__ A0, const ushort* __restrict__ A1,
    const ushort* __restrict__ B0, const ushort* __restrict__ B1,
    const float* __restrict__ bias, const float* __restrict__ g,
    const float* __restrict__ b, float* __restrict__ h, ushort* __restrict__ hb,
    int do_ln) {
  __shared__ ushort Alds[32][40];
  __shared__ ushort Blds[256][40];
  int t = threadIdx.x;
  int w = t >> 6, l = t & 63, quad = l >> 4, lr = l & 15;
  int m0 = blockIdx.x * 32;
  int sr = (t >> 2) & 31, sc8 = (t & 3) * 8;
  f32x4_t acc[2][4];
#pragma unroll
  for (int s = 0; s < 2; ++s)
#pragma unroll
    for (int q = 0; q < 4; ++q) acc[s][q] = (f32x4_t){0.f, 0.f, 0.f, 0.f};

  for (int k0 = 0; k0 < 512; k0 += 32) {
    uint4 av = make_uint4(0u, 0u, 0u, 0u);
    if (t < 128) {
      int kk = k0 + sc8;
      av = (kk < 256) ? *(const uint4*)(A0 + (size_t)(m0 + sr) * 256 + kk)
                      : *(const uint4*)(A1 + (size_t)(m0 + sr) * 256 + kk - 256);
    }
    uint4 bv[4];
#pragma unroll
    for (int c = 0; c < 4; ++c) {
      int kk = k0 + c * 8;
      bv[c] = (kk < 256) ? *(const uint4*)(B0 + (size_t)t * 256 + kk)
                         : *(const uint4*)(B1 + (size_t)t * 256 + kk - 256);
    }
    __syncthreads();
    if (t < 128) *(uint4*)&Alds[sr][sc8] = av;
#pragma unroll
    for (int c = 0; c < 4; ++c) *(uint4*)&Blds[t][c * 8] = bv[c];
    __syncthreads();
    bf16x8_t af[2], bf[4];
#pragma unroll
    for (int s = 0; s < 2; ++s)
      af[s] = *(const bf16x8_t*)&Alds[s * 16 + lr][quad * 8];
#pragma unroll
    for (int q = 0; q < 4; ++q)
      bf[q] = *(const bf16x8_t*)&Blds[w * 64 + q * 16 + lr][quad * 8];
#pragma unroll
    for (int s = 0; s < 2; ++s)
#pragma unroll
      for (int q = 0; q < 4; ++q)
        acc[s][q] = __builtin_amdgcn_mfma_f32_16x16x32_bf16(af[s], bf[q], acc[s][q], 0, 0, 0);
  }
  // + bias (pre-LN value)
#pragma unroll
  for (int s = 0; s < 2; ++s)
#pragma unroll
    for (int q = 0; q < 4; ++q) {
      float bb = bias[w * 64 + q * 16 + lr];
#pragma unroll
      for (int r = 0; r < 4; ++r) acc[s][q][r] += bb;
    }
  // block-wide LN over each of the 32 rows (cols split: lanes x 4 waves)
  float m_[2][4], inv_[2][4];
  if (do_ln) {
    float rs[2][4] = {{0.f, 0.f, 0.f, 0.f}, {0.f, 0.f, 0.f, 0.f}};
    float rq[2][4] = {{0.f, 0.f, 0.f, 0.f}, {0.f, 0.f, 0.f, 0.f}};
#pragma unroll
    for (int s = 0; s < 2; ++s)
#pragma unroll
      for (int q = 0; q < 4; ++q)
#pragma unroll
        for (int r = 0; r < 4; ++r) {
          float v = acc[s][q][r];
          rs[s][r] += v; rq[s][r] += v * v;
        }
#pragma unroll
    for (int mask = 1; mask < 16; mask <<= 1)
#pragma unroll
      for (int s = 0; s < 2; ++s)
#pragma unroll
        for (int r = 0; r < 4; ++r) {
          rs[s][r] += __shfl_xor(rs[s][r], mask);
          rq[s][r] += __shfl_xor(rq[s][r], mask);
        }
    __syncthreads();  // LDS frags fully consumed; overlay Alds with reduction scratch
    float* redS = (float*)&Alds[0][0];  // [4][32]
    float* redQ = redS + 128;           // [4][32]
    if (lr == 0) {
#pragma unroll
      for (int s = 0; s < 2; ++s)
#pragma unroll
        for (int r = 0; r < 4; ++r) {
          int row = s * 16 + quad * 4 + r;
          redS[w * 32 + row] = rs[s][r];
          redQ[w * 32 + row] = rq[s][r];
        }
    }
    __syncthreads();
#pragma unroll
    for (int s = 0; s < 2; ++s)
#pragma unroll
      for (int r = 0; r < 4; ++r) {
        int row = s * 16 + quad * 4 + r;
        float S = redS[row] + redS[32 + row] + redS[64 + row] + redS[96 + row];
        float Q = redQ[row] + redQ[32 + row] + redQ[64 + row] + redQ[96 + row];
        float mm = S * (1.f / 256.f);
        float vv = Q * (1.f / 256.f) - mm * mm;
        m_[s][r] = mm;
        inv_[s][r] = rsqrtf(vv + LN_EPS);
      }
  }
#pragma unroll
  for (int s = 0; s < 2; ++s)
#pragma unroll
    for (int q = 0; q < 4; ++q) {
      int colc = w * 64 + q * 16 + lr;
      float gg = do_ln ? g[colc] : 0.f;
      float bb2 = do_ln ? b[colc] : 0.f;
#pragma unroll
      for (int r = 0; r < 4; ++r) {
        int row = m0 + s * 16 + quad * 4 + r;
        float y = acc[s][q][r];
        if (do_ln) y = (y - m_[s][r]) * inv_[s][r] * gg + bb2;
        y = fmaxf(y, 0.f) + h[(size_t)row * 256 + colc];
        h[(size_t)row * 256 + colc] = y;
        hb[(size_t)row * 256 + colc] = f2b(y);
      }
    }
}

// ---------------- conv layer fully fused: conv-GEMM(K=768) + bias + relu + LN, bf16 out ----------------
__global__ __launch_bounds__(256) void conv_fused(
    const ushort* __restrict__ Ab, const ushort* __restrict__ B,
    const float* __restrict__ bias, const float* __restrict__ g,
    const float* __restrict__ b, ushort* __restrict__ outb) {
  __shared__ ushort Alds[32][40];
  __shared__ ushort Blds[256][40];
  int t = threadIdx.x;
  int w = t >> 6, l = t & 63, quad = l >> 4, lr = l & 15;
  int m0 = blockIdx.x * 32;
  int sr = (t >> 2) & 31, sc8 = (t & 3) * 8;
  f32x4_t acc[2][4];
#pragma unroll
  for (int s = 0; s < 2; ++s)
#pragma unroll
    for (int q = 0; q < 4; ++q) acc[s][q] = (f32x4_t){0.f, 0.f, 0.f, 0.f};

  for (int k0 = 0; k0 < 768; k0 += 32) {
    uint4 av = make_uint4(0u, 0u, 0u, 0u);
    if (t < 128) {
      int kk = k0 + sc8;
      int ks = kk >> 8, ii = kk & 255;
      int nr = m0 + sr + ks - 1;
      if (nr >= 0 && nr < NN) av = *(const uint4*)(Ab + (size_t)nr * 256 + ii);
    }
    uint4 bv[4];
#pragma unroll
    for (int c = 0; c < 4; ++c)
      bv[c] = *(const uint4*)(B + (size_t)t * 768 + k0 + c * 8);
    __syncthreads();
    if (t < 128) *(uint4*)&Alds[sr][sc8] = av;
#pragma unroll
    for (int c = 0; c < 4; ++c) *(uint4*)&Blds[t][c * 8] = bv[c];
    __syncthreads();
    bf16x8_t af[2], bf[4];
#pragma unroll
    for (int s = 0; s < 2; ++s)
      af[s] = *(const bf16x8_t*)&Alds[s * 16 + lr][quad * 8];
#pragma unroll
    for (int q = 0; q < 4; ++q)
      bf[q] = *(const bf16x8_t*)&Blds[w * 64 + q * 16 + lr][quad * 8];
#pragma unroll
    for (int s = 0; s < 2; ++s)
#pragma unroll
      for (int q = 0; q < 4; ++q)
        acc[s][q] = __builtin_amdgcn_mfma_f32_16x16x32_bf16(af[s], bf[q], acc[s][q], 0, 0, 0);
  }
  // relu(v + bias) is the LN input
#pragma unroll
  for (int s = 0; s < 2; ++s)
#pragma unroll
    for (int q = 0; q < 4; ++q) {
      float bb = bias[w * 64 + q * 16 + lr];
#pragma unroll
      for (int r = 0; r < 4; ++r) acc[s][q][r] = fmaxf(acc[s][q][r] + bb, 0.f);
    }
  float rs[2][4] = {{0.f, 0.f, 0.f, 0.f}, {0.f, 0.f, 0.f, 0.f}};
  float rq[2][4] = {{0.f, 0.f, 0.f, 0.f}, {0.f, 0.f, 0.f, 0.f}};
#pragma unroll
  for (int s = 0; s < 2; ++s)
#pragma unroll
    for (int q = 0; q < 4; ++q)
#pragma unroll
      for (int r = 0; r < 4; ++r) {
        float v = acc[s][q][r];
        rs[s][r] += v; rq[s][r] += v * v;
      }
#pragma unroll
  for (int mask = 1; mask < 16; mask <<= 1)
#pragma unroll
    for (int s = 0; s < 2; ++s)
#pragma unroll
      for (int r = 0; r < 4; ++r) {
        rs[s][r] += __shfl_xor(rs[s][r], mask);
        rq[s][r] += __shfl_xor(rq[s][r], mask);
      }
  __syncthreads();
  float* redS = (float*)&Alds[0][0];
  float* redQ = redS + 128;
  if (lr == 0) {
#pragma unroll
    for (int s = 0; s < 2; ++s)
#pragma unroll
      for (int r = 0; r < 4; ++r) {
        int row = s * 16 + quad * 4 + r;
        redS[w * 32 + row] = rs[s][r];
        redQ[w * 32 + row] = rq[s][r];
      }
  }
  __syncthreads();
#pragma unroll
  for (int s = 0; s < 2; ++s)
#pragma unroll
    for (int q = 0; q < 4; ++q) {
      int colc = w * 64 + q * 16 + lr;
      float gg = g[colc], bb2 = b[colc];
#pragma unroll
      for (int r = 0; r < 4; ++r) {
        int row = s * 16 + quad * 4 + r;
        float S = redS[row] + redS[32 + row] + redS[64 + row] + redS[96 + row];
        float Q = redQ[row] + redQ[32 + row] + redQ[64 + row] + redQ[96 + row];
        float mm = S * (1.f / 256.f);
        float vv = Q * (1.f / 256.f) - mm * mm;
        float y = (acc[s][q][r] - mm) * rsqrtf(vv + LN_EPS) * gg + bb2;
        outb[(size_t)(m0 + row) * 256 + colc] = f2b(y);
      }
    }
}

// ---------------- fp32 tiled GEMM (fuse head only) ----------------
__global__ __launch_bounds__(256) void gemm_std(
    const float* __restrict__ A0, const float* __restrict__ B0,
    const float* __restrict__ bias, float* __restrict__ C,
    int M, int Nn, int K) {
  __shared__ float As[16][68];
  __shared__ float Bs[16][68];
  int t = threadIdx.x;
  int m0 = blockIdx.x * 64, n0 = blockIdx.y * 64;
  int ty = t >> 4, tx = t & 15;
  int lr = t >> 2, lc4 = (t & 3) * 4;
  float acc[4][4] = {};
  for (int k0 = 0; k0 < K; k0 += 16) {
    int kk = k0 + lc4;
    float4 va = *(const float4*)(A0 + (size_t)(m0 + lr) * K + kk);
    As[lc4 + 0][lr] = va.x; As[lc4 + 1][lr] = va.y;
    As[lc4 + 2][lr] = va.z; As[lc4 + 3][lr] = va.w;
    float4 vb = *(const float4*)(B0 + (size_t)(n0 + lr) * K + kk);
    Bs[lc4 + 0][lr] = vb.x; Bs[lc4 + 1][lr] = vb.y;
    Bs[lc4 + 2][lr] = vb.z; Bs[lc4 + 3][lr] = vb.w;
    __syncthreads();
#pragma unroll
    for (int k = 0; k < 16; ++k) {
      float4 a4 = *(const float4*)&As[k][4 * ty];
      float4 b4 = *(const float4*)&Bs[k][4 * tx];
      float av[4] = {a4.x, a4.y, a4.z, a4.w};
      float bv[4] = {b4.x, b4.y, b4.z, b4.w};
#pragma unroll
      for (int i = 0; i < 4; ++i)
#pragma unroll
        for (int j = 0; j < 4; ++j) acc[i][j] += av[i] * bv[j];
    }
    __syncthreads();
  }
#pragma unroll
  for (int i = 0; i < 4; ++i) {
    int m = m0 + 4 * ty + i;
    float o[4];
#pragma unroll
    for (int j = 0; j < 4; ++j) o[j] = acc[i][j] + bias[n0 + 4 * tx + j];
    float4 o4 = make_float4(o[0], o[1], o[2], o[3]);
    *(float4*)(C + (size_t)m * Nn + n0 + 4 * tx) = o4;
  }
}

// ---------------- fused LayerNorm (attention out only, D=512) ----------------
__global__ __launch_bounds__(256) void ln_fuse(
    const float* __restrict__ x, const float* __restrict__ g, const float* __restrict__ b,
    float* __restrict__ outf, int D) {
  int row = blockIdx.x, t = threadIdx.x;
  int nv = D >> 8;
  float vals[2];
  float s = 0.f, sq = 0.f;
  for (int u = 0; u < nv; ++u) {
    float v = x[(size_t)row * D + t + (u << 8)];
    vals[u] = v; s += v; sq += v * v;
  }
  __shared__ float red[8];
  for (int off = 32; off >= 1; off >>= 1) {
    s += __shfl_xor(s, off);
    sq += __shfl_xor(sq, off);
  }
  int wid = t >> 6;
  if ((t & 63) == 0) { red[wid] = s; red[4 + wid] = sq; }
  __syncthreads();
  if (t == 0) {
    float S = red[0] + red[1] + red[2] + red[3];
    float Q = red[4] + red[5] + red[6] + red[7];
    float mm = S / D;
    float vv = Q / D - mm * mm;
    red[0] = mm;
    red[1] = rsqrtf(vv + LN_EPS);
  }
  __syncthreads();
  float m = red[0], inv = red[1];
  for (int u = 0; u < nv; ++u) {
    int c = t + (u << 8);
    float y = (vals[u] - m) * inv * g[c] + b[c];
    outf[(size_t)row * D + c] = y;
  }
}

// ---------------- K/V repack for fragment-direct attention ----------------
__global__ __launch_bounds__(256) void kvpack(const ushort* __restrict__ qkvb,
                                              ushort* __restrict__ Kt,
                                              ushort* __restrict__ VtT) {
  int t = threadIdx.x;
  int n0 = blockIdx.x * 32;
  int by = blockIdx.y;
  int kt = n0 >> 5;
  {
    int head = by >> 2, ks = by & 3;
    int key = t >> 3, e4 = (t & 7) * 4;
    uint2 v = *(const uint2*)(qkvb + (size_t)(n0 + key) * 1536 + 512 + head * 128 + ks * 32 + e4);
    *(uint2*)(Kt + ((((size_t)head * 128 + kt) * 4 + ks) * 32 + key) * 32 + e4) = v;
  }
  __shared__ ushort tile[32][34];
  int d0 = by * 32;
  int tx = t & 31, ty = t >> 5;
#pragma unroll
  for (int u = 0; u < 4; ++u) {
    int r = ty + 8 * u;
    tile[r][tx] = qkvb[(size_t)(n0 + r) * 1536 + 1024 + d0 + tx];
  }
  __syncthreads();
#pragma unroll
  for (int u = 0; u < 4; ++u) {
    int dg = d0 + ty + 8 * u;
    int head = dg >> 7, dl = dg & 127;
    VtT[((((size_t)head * 128 + kt) * 128 + dl) << 5) + tx] = tile[tx][ty + 8 * u];
  }
}

// ---------------- bf16 MFMA flash attention (R4 version, proven 73.6us) ----------------
__global__ __launch_bounds__(256, 2) void attn_mfma(const ushort* __restrict__ qkvb,
                                                    const ushort* __restrict__ Kt,
                                                    const ushort* __restrict__ VtT,
                                                    ushort* __restrict__ Ob) {
  __shared__ __align__(16) char smem[66048];
  int t = threadIdx.x;
  int w = t >> 6, l = t & 63;
  int quad = l >> 4, lr = l & 15;
  int head = blockIdx.y;
  int q0 = blockIdx.x * 32;

  ushort* Pl = (ushort*)smem + w * 1280;

  bf16x8_t qf[2][4];
#pragma unroll
  for (int s = 0; s < 2; ++s)
#pragma unroll
    for (int ks = 0; ks < 4; ++ks)
      qf[s][ks] = *(const bf16x8_t*)(qkvb + (size_t)(q0 + s * 16 + lr) * 1536 +
                                     head * 128 + ks * 32 + quad * 8);

  f32x4_t of[2][8];
#pragma unroll
  for (int s = 0; s < 2; ++s)
#pragma unroll
    for (int dt = 0; dt < 8; ++dt) of[s][dt] = (f32x4_t){0.f, 0.f, 0.f, 0.f};
  float den[2][4] = {{0.f, 0.f, 0.f, 0.f}, {0.f, 0.f, 0.f, 0.f}};

  const int lnoff = lr * 32 + quad * 8;
  const int tile0 = w * 32;

  bf16x8_t kfA[4][2];
  {
    const ushort* kb = Kt + (((size_t)head * 128 + tile0) << 12);
#pragma unroll
    for (int ks = 0; ks < 4; ++ks)
#pragma unroll
      for (int ct = 0; ct < 2; ++ct)
        kfA[ks][ct] = *(const bf16x8_t*)(kb + ks * 1024 + ct * 512 + lnoff);
  }

#pragma unroll 2
  for (int tt = 0; tt < 32; ++tt) {
    int kt = tile0 + tt;
    const ushort* vbase = VtT + (((size_t)head * 128 + kt) << 12);

    bf16x8_t vf[8];
#pragma unroll
    for (int dt = 0; dt < 8; ++dt)
      vf[dt] = *(const bf16x8_t*)(vbase + dt * 512 + lnoff);

    bf16x8_t kfB[4][2];
    if (tt < 31) {
      const ushort* kb = Kt + (((size_t)head * 128 + kt + 1) << 12);
#pragma unroll
      for (int ks = 0; ks < 4; ++ks)
#pragma unroll
        for (int ct = 0; ct < 2; ++ct)
          kfB[ks][ct] = *(const bf16x8_t*)(kb + ks * 1024 + ct * 512 + lnoff);
    }

    f32x4_t sf[2][2];
#pragma unroll
    for (int s = 0; s < 2; ++s)
#pragma unroll
      for (int ct = 0; ct < 2; ++ct) sf[s][ct] = (f32x4_t){0.f, 0.f, 0.f, 0.f};
    __builtin_amdgcn_s_setprio(1);
#pragma unroll
    for (int ks = 0; ks < 4; ++ks)
#pragma unroll
      for (int ct = 0; ct < 2; ++ct)
#pragma unroll
        for (int s = 0; s < 2; ++s)
          sf[s][ct] = __builtin_amdgcn_mfma_f32_16x16x32_bf16(qf[s][ks], kfA[ks][ct], sf[s][ct], 0, 0, 0);
    __builtin_amdgcn_s_setprio(0);

#pragma unroll
    for (int s = 0; s < 2; ++s)
#pragma unroll
      for (int ct = 0; ct < 2; ++ct)
#pragma unroll
        for (int r = 0; r < 4; ++r) {
          float e = __expf(sf[s][ct][r] * ATT_SCALE - ATT_SHIFT);
          Pl[(s * 16 + quad * 4 + r) * 40 + ct * 16 + lr] = f2b(e);
          den[s][r] += e;
        }

    __builtin_amdgcn_s_setprio(1);
#pragma unroll
    for (int s = 0; s < 2; ++s) {
      bf16x8_t pf = *(const bf16x8_t*)&Pl[(s * 16 + lr) * 40 + quad * 8];
#pragma unroll
      for (int dt = 0; dt < 8; ++dt)
        of[s][dt] = __builtin_amdgcn_mfma_f32_16x16x32_bf16(pf, vf[dt], of[s][dt], 0, 0, 0);
    }
    __builtin_amdgcn_s_setprio(0);

    if (tt < 31) {
#pragma unroll
      for (int ks = 0; ks < 4; ++ks)
#pragma unroll
        for (int ct = 0; ct < 2; ++ct) kfA[ks][ct] = kfB[ks][ct];
    }
  }

#pragma unroll
  for (int mask = 1; mask < 16; mask <<= 1)
#pragma unroll
    for (int s = 0; s < 2; ++s)
#pragma unroll
      for (int r = 0; r < 4; ++r) den[s][r] += __shfl_xor(den[s][r], mask);

  __syncthreads();
  float* Osum = (float*)smem;
  float* Dsum = (float*)(smem + 65536);
#pragma unroll
  for (int s = 0; s < 2; ++s)
#pragma unroll
    for (int dt = 0; dt < 8; ++dt)
#pragma unroll
      for (int r = 0; r < 4; ++r)
        Osum[w * 4096 + (s * 16 + quad * 4 + r) * 128 + dt * 16 + lr] = of[s][dt][r];
  if (lr == 0) {
#pragma unroll
    for (int s = 0; s < 2; ++s)
#pragma unroll
      for (int r = 0; r < 4; ++r) Dsum[w * 32 + s * 16 + quad * 4 + r] = den[s][r];
  }
  __syncthreads();
#pragma unroll
  for (int e = 0; e < 16; ++e) {
    int idx = l + e * 64;
    int row = w * 8 + (idx >> 7), col = idx & 127;
    float o = Osum[row * 128 + col] + Osum[4096 + row * 128 + col] +
              Osum[8192 + row * 128 + col] + Osum[12288 + row * 128 + col];
    float dn = Dsum[row] + Dsum[32 + row] + Dsum[64 + row] + Dsum[96 + row];
    Ob[(size_t)(q0 + row) * 512 + head * 128 + col] = f2b(o / dn);
  }
}

// ---------------- launch ----------------
extern "C" void kernel_launch(void* const* d_in, const int* in_sizes, int n_in,
                              void* d_out, int out_size, void* d_ws, size_t ws_size,
                              hipStream_t stream) {
  const float* x          = (const float*)d_in[0];
  const int*   ei         = (const int*)d_in[1];
  const float* sage_wl    = (const float*)d_in[2];
  const float* sage_wr    = (const float*)d_in[3];
  const float* sage_bl    = (const float*)d_in[4];
  const float* ln_g       = (const float*)d_in[5];
  const float* ln_b       = (const float*)d_in[6];
  const float* conv_w     = (const float*)d_in[7];
  const float* conv_b     = (const float*)d_in[8];
  const float* cnorm_g    = (const float*)d_in[9];
  const float* cnorm_b    = (const float*)d_in[10];
  const float* in_proj_w  = (const float*)d_in[11];
  const float* in_proj_b  = (const float*)d_in[12];
  const float* out_proj_w = (const float*)d_in[13];
  const float* out_proj_b = (const float*)d_in[14];
  const float* anorm_g    = (const float*)d_in[15];
  const float* anorm_b    = (const float*)d_in[16];
  const float* fuse_w     = (const float*)d_in[17];
  const float* fuse_b     = (const float*)d_in[18];
  float* out = (float*)d_out;

  char* ws = (char*)d_ws;
  const size_t MB = 1 << 20;
  int*    rowptr = (int*)(ws + 0);
  int*    cnt    = (int*)(ws + 65536);
  int*    col    = (int*)(ws + 131072);
  float*  invdeg = (float*)(ws + 786432);
  float*  h    = (float*)(ws + 1 * MB);
  ushort* hb   = (ushort*)(ws + 5 * MB);
  ushort* aggb = (ushort*)(ws + 7 * MB);
  ushort* c0b  = (ushort*)(ws + 13 * MB);
  ushort* c1b  = (ushort*)(ws + 15 * MB);
  ushort* qkvb = (ushort*)(ws + 17 * MB);
  float*  op   = (float*)(ws + 17 * MB);    // reuses qkvb after attention
  ushort* Kt   = (ushort*)(ws + 1 * MB);    // reuses h (dead after GNN): 4MB
  ushort* Vt   = (ushort*)(ws + 29 * MB);   // VtT tile-major V (4MB)
  ushort* aob  = (ushort*)(ws + 33 * MB);
  ushort* wlb  = (ushort*)(ws + 37 * MB);            // 786KB
  ushort* wrb  = (ushort*)(ws + 37 * MB + 786432);   // 786KB
  ushort* cvb  = (ushort*)(ws + 37 * MB + 1572864);  // 1.125MB
  ushort* ipb  = (ushort*)(ws + 37 * MB + 2752512);  // 1.5MB
  ushort* opb  = (ushort*)(ws + 37 * MB + 4325376);  // 0.5MB

  // all weight casts, one launch
  castall<<<2368, 256, 0, stream>>>(sage_wl, sage_wr, conv_w, in_proj_w, out_proj_w,
                                    wlb, wrb, cvb, ipb, opb);

  // CSR
  hipMemsetAsync(cnt, 0, NN * sizeof(int), stream);
  hist_kernel<<<EE / 256, 256, 0, stream>>>(ei, cnt);
  scan_kernel<<<1, 1024, 0, stream>>>(cnt, rowptr, invdeg);
  fill_kernel<<<EE / 256, 256, 0, stream>>>(ei, cnt, col);
  copycast<<<(NN * HH) / 1024, 256, 0, stream>>>(x, h, hb);

  // GNN: 6 SAGE layers, fully fused (agg + gemm/LN/relu/res)
  for (int i = 0; i < 6; ++i) {
    agg_kernel<<<NN, 64, 0, stream>>>(hb, rowptr, col, invdeg, aggb);
    int do_ln = (i < 5) ? 1 : 0;
    const float* gp = do_ln ? (ln_g + i * HH) : ln_g;
    const float* bp = do_ln ? (ln_b + i * HH) : ln_b;
    sage_fused<<<128, 256, 0, stream>>>(
        aggb, hb, wlb + (size_t)i * HH * HH, wrb + (size_t)i * HH * HH,
        sage_bl + i * HH, gp, bp, h, hb, do_ln);
  }

  // CNN: 3 conv layers, fully fused
  const ushort* cin = hb;
  ushort* couts[3] = {c0b, c1b, c0b};
  for (int j = 0; j < 3; ++j) {
    conv_fused<<<128, 256, 0, stream>>>(
        cin, cvb + (size_t)j * HH * 768, conv_b + j * HH,
        cnorm_g + j * HH, cnorm_b + j * HH, couts[j]);
    cin = couts[j];
  }

  // attention
  gemm_mfma<<<dim3(64, 12), 256, 0, stream>>>(
      hb, c0b, ipb, nullptr, in_proj_b, nullptr, qkvb, NN, 1536, 512, 256, 512, 0);
  kvpack<<<dim3(NN / 32, 16), 256, 0, stream>>>(qkvb, Kt, Vt);
  attn_mfma<<<dim3(NN / 32, 4), 256, 0, stream>>>(qkvb, Kt, Vt, aob);

  gemm_mfma<<<dim3(64, 4), 256, 0, stream>>>(
      aob, nullptr, opb, nullptr, out_proj_b, op, nullptr, NN, 512, 512, 512, 512, 0);
  ln_fuse<<<NN, 256, 0, stream>>>(op, anorm_g, anorm_b, op, 512);
  gemm_std<<<dim3(64, 1), 256, 0, stream>>>(op, fuse_w, fuse_b, out, NN, 64, 512);
}